// Round 1
// 758.483 us; speedup vs baseline: 2.4411x; 2.4411x over previous
//
#include <hip/hip_runtime.h>

#define VN 6890
#define TN 100
#define NOUT 800   // 8 rotations * 100 templates
#define MP 6912    // VN padded to 54*128
#define NP 896     // NOUT padded to 7*128

typedef __attribute__((ext_vector_type(8))) short bf16x8;
typedef __attribute__((ext_vector_type(4))) float f32x4;

// ---------------------------------------------------------------------------
// helpers
__device__ __forceinline__ unsigned short f2bf(float f) {
    unsigned u = __float_as_uint(f);
    return (unsigned short)((u + 0x7FFFu + ((u >> 16) & 1u)) >> 16);
}
__device__ __forceinline__ void split_bf16(float f, short* h, short* l) {
    unsigned short hb = f2bf(f);
    float hf = __uint_as_float(((unsigned)hb) << 16);
    *h = (short)hb;
    *l = (short)f2bf(f - hf);
}
__device__ __forceinline__ void gload16(const short* g, void* lds) {
    __builtin_amdgcn_global_load_lds(
        (const __attribute__((address_space(1))) void*)g,
        (__attribute__((address_space(3))) void*)lds, 16, 0, 0);
}

// ---------------------------------------------------------------------------
// x0[v,c] = (signal[v,c] - mean[c]) / sqrt(var[c])
__global__ __launch_bounds__(256) void norm_kernel(
    const float* __restrict__ sig, const float* __restrict__ mean,
    const float* __restrict__ var, float* __restrict__ x0)
{
    int i = blockIdx.x * blockDim.x + threadIdx.x;
    if (i < VN * 3) {
        int c = i % 3;
        x0[i] = (sig[i] - mean[c]) / sqrtf(var[c]);
    }
}

// ---------------------------------------------------------------------------
// Rotated weights, TRANSPOSED + split:  Bt[n][k] = W[t, r, (a+rot)&7, c]
// n = rot*100 + t (padded to NP with zeros), k = (r*8+a)*CIN + c (padded to KPAD).
template<int CIN, int KPAD>
__global__ __launch_bounds__(256) void rotw_split(
    const float* __restrict__ W, short* __restrict__ Bh, short* __restrict__ Bl)
{
    const int n = blockIdx.x;          // 0..NP-1
    const int K = 40 * CIN;
    const int rot = n / TN, t = n - rot * TN;
    for (int k = threadIdx.x; k < KPAD; k += 256) {
        float w = 0.f;
        if (n < NOUT && k < K) {
            int ra = k / CIN, c = k - ra * CIN;
            int r = ra >> 3, a = ra & 7;
            int a2 = (a + rot) & 7;
            w = W[((t * 5 + r) * 8 + a2) * CIN + c];
        }
        short h, l; split_bf16(w, &h, &l);
        Bh[(size_t)n * KPAD + k] = h;
        Bl[(size_t)n * KPAD + k] = l;
    }
}

// ---------------------------------------------------------------------------
// Barycentric patch, split to bf16 hi/lo:  P[v][ra*CIN+c], rows padded to MP.
template<int CIN, int KPAD>
__global__ __launch_bounds__(256) void patch_split(
    const float* __restrict__ x, const int* __restrict__ bidx,
    const float* __restrict__ bw, short* __restrict__ Ph, short* __restrict__ Pl)
{
    __shared__ int   sIdx[120];
    __shared__ float sW[120];
    const int v = blockIdx.x;
    const int tid = threadIdx.x;
    const int K = 40 * CIN;
    if (v >= VN) {   // zero-pad rows (block-uniform branch)
        for (int e = tid; e < KPAD; e += 256) {
            Ph[(size_t)v * KPAD + e] = 0;
            Pl[(size_t)v * KPAD + e] = 0;
        }
        return;
    }
    if (tid < 120) { sIdx[tid] = bidx[v * 120 + tid]; sW[tid] = bw[v * 120 + tid]; }
    __syncthreads();
    for (int e = tid; e < KPAD; e += 256) {
        float s = 0.f;
        if (e < K) {
            int ra = e / CIN, c = e - ra * CIN;
            s = sW[ra * 3 + 0] * x[sIdx[ra * 3 + 0] * CIN + c]
              + sW[ra * 3 + 1] * x[sIdx[ra * 3 + 1] * CIN + c]
              + sW[ra * 3 + 2] * x[sIdx[ra * 3 + 2] * CIN + c];
        }
        short h, l; split_bf16(s, &h, &l);
        Ph[(size_t)v * KPAD + e] = h;
        Pl[(size_t)v * KPAD + e] = l;
    }
}

// ---------------------------------------------------------------------------
// Split-bf16 MFMA GEMM:  C = A @ B^T  with A=(Ah+Al), B^T rows=(Bh+Bl), both (rows x K)
// 3-product Markidis: acc = Ah·Bh + Ah·Bl + Al·Bh  (fp32 MFMA accumulate).
// 128x128 tile, BK=32, 256 threads (4 waves, 2x2), 4x4 16x16x32 frags per wave.
// LDS: linear dest for global_load_lds; XOR swizzle (chunk ^= (row>>1)&3) applied
// to the GLOBAL source and to the ds_read_b128 address (same involution).
// CONV_EPI: bias[n%100]+relu, no guards (C is MP x NP scratch).
// else: bias[n], guarded stores (C is the real out, ldc=N=VN).
template<bool CONV_EPI>
__global__ __launch_bounds__(256, 2) void mfma_gemm(
    const short* __restrict__ Ah, const short* __restrict__ Al,
    const short* __restrict__ Bh, const short* __restrict__ Bl,
    const float* __restrict__ bias, float* __restrict__ C,
    int M, int N, int ldc, int K)
{
    __shared__ __align__(16) short AhS[4096];   // 128 rows x 32 bf16 (64B rows)
    __shared__ __align__(16) short AlS[4096];
    __shared__ __align__(16) short BhS[4096];
    __shared__ __align__(16) short BlS[4096];

    const int tid  = threadIdx.x;
    const int wave = tid >> 6;
    const int lane = tid & 63;
    const int lr = lane & 15, lg = lane >> 4;
    const int wm = wave >> 1, wn = wave & 1;
    const int m0 = blockIdx.x * 128;
    const int n0 = blockIdx.y * 128;

    // staging source offsets (inverse-swizzled): LDS byte off = row*64 + p*16,
    // physical chunk p holds logical k-chunk g = p ^ ((row>>1)&3)
    const int off0 = tid * 16, off1 = off0 + 4096;
    const int row0 = off0 >> 6, row1 = off1 >> 6;
    const int g0 = ((off0 >> 4) & 3) ^ ((row0 >> 1) & 3);
    const int g1 = ((off1 >> 4) & 3) ^ ((row1 >> 1) & 3);
    const size_t aO0 = (size_t)(m0 + row0) * K + g0 * 8;
    const size_t aO1 = (size_t)(m0 + row1) * K + g1 * 8;
    const size_t bO0 = (size_t)(n0 + row0) * K + g0 * 8;
    const size_t bO1 = (size_t)(n0 + row1) * K + g1 * 8;
    const int wofs = wave << 10;

    // swizzled ds_read byte offsets (loop-invariant)
    int aRd[4], bRd[4];
    #pragma unroll
    for (int f = 0; f < 4; ++f) {
        int ar = wm * 64 + f * 16 + lr;
        aRd[f] = ar * 64 + ((lg ^ ((ar >> 1) & 3)) << 4);
        int br = wn * 64 + f * 16 + lr;
        bRd[f] = br * 64 + ((lg ^ ((br >> 1) & 3)) << 4);
    }

    f32x4 acc[4][4];
    #pragma unroll
    for (int i = 0; i < 4; ++i)
        #pragma unroll
        for (int j = 0; j < 4; ++j)
            acc[i][j] = (f32x4){0.f, 0.f, 0.f, 0.f};

    const int nkt = K >> 5;
    for (int kt = 0; kt < nkt; ++kt) {
        const int k0 = kt << 5;
        gload16(Ah + aO0 + k0, (char*)AhS + wofs);
        gload16(Ah + aO1 + k0, (char*)AhS + 4096 + wofs);
        gload16(Al + aO0 + k0, (char*)AlS + wofs);
        gload16(Al + aO1 + k0, (char*)AlS + 4096 + wofs);
        gload16(Bh + bO0 + k0, (char*)BhS + wofs);
        gload16(Bh + bO1 + k0, (char*)BhS + 4096 + wofs);
        gload16(Bl + bO0 + k0, (char*)BlS + wofs);
        gload16(Bl + bO1 + k0, (char*)BlS + 4096 + wofs);
        __syncthreads();   // compiler drains vmcnt(0) before s_barrier

        bf16x8 ah[4], al[4], bh[4], bl[4];
        #pragma unroll
        for (int f = 0; f < 4; ++f) {
            ah[f] = *(const bf16x8*)((const char*)AhS + aRd[f]);
            al[f] = *(const bf16x8*)((const char*)AlS + aRd[f]);
            bh[f] = *(const bf16x8*)((const char*)BhS + bRd[f]);
            bl[f] = *(const bf16x8*)((const char*)BlS + bRd[f]);
        }
        // three passes keep the 16-MFMA dependency distance per accumulator
        #pragma unroll
        for (int i = 0; i < 4; ++i)
            #pragma unroll
            for (int j = 0; j < 4; ++j)
                acc[i][j] = __builtin_amdgcn_mfma_f32_16x16x32_bf16(ah[i], bh[j], acc[i][j], 0, 0, 0);
        #pragma unroll
        for (int i = 0; i < 4; ++i)
            #pragma unroll
            for (int j = 0; j < 4; ++j)
                acc[i][j] = __builtin_amdgcn_mfma_f32_16x16x32_bf16(ah[i], bl[j], acc[i][j], 0, 0, 0);
        #pragma unroll
        for (int i = 0; i < 4; ++i)
            #pragma unroll
            for (int j = 0; j < 4; ++j)
                acc[i][j] = __builtin_amdgcn_mfma_f32_16x16x32_bf16(al[i], bh[j], acc[i][j], 0, 0, 0);
        __syncthreads();
    }

    // epilogue: D row = lg*4+q, col = lr  (m89-verified C/D layout)
    #pragma unroll
    for (int i = 0; i < 4; ++i) {
        const int mb = m0 + wm * 64 + i * 16 + lg * 4;
        #pragma unroll
        for (int j = 0; j < 4; ++j) {
            const int n = n0 + wn * 64 + j * 16 + lr;
            if (CONV_EPI) {
                const float bv = bias[n % TN];
                #pragma unroll
                for (int q = 0; q < 4; ++q)
                    C[(size_t)(mb + q) * ldc + n] = fmaxf(acc[i][j][q] + bv, 0.f);
            } else {
                if (n < N) {
                    const float bv = bias[n];
                    #pragma unroll
                    for (int q = 0; q < 4; ++q)
                        if (mb + q < M)
                            C[(size_t)(mb + q) * ldc + n] = acc[i][j][q] + bv;
                }
            }
        }
    }
}

// ---------------------------------------------------------------------------
// fp32 fallback SGEMM for the dense head (used only if workspace is too small
// for the split-bf16 dense scratch). Unchanged from previous round.
template<bool CONV_EPI>
__global__ __launch_bounds__(256, 4) void tile_gemm(
    const float* __restrict__ A, const float* __restrict__ B,
    const float* __restrict__ bias, float* __restrict__ C,
    int M, int N, int K)
{
    __shared__ __align__(16) float As[32][132];
    __shared__ __align__(16) float Bs[32][68];

    const int tid = threadIdx.x;
    const int m0 = blockIdx.x * 128;
    const int n0 = blockIdx.y * 64;
    const int ty = tid >> 4;
    const int tx = tid & 15;
    const int nkt = (K + 31) >> 5;

    float4 aR[4];
    float2 bR[4];

    auto load_tile = [&](int kt) {
        const int k0 = kt << 5;
        #pragma unroll
        for (int j = 0; j < 4; ++j) {
            int q = tid + 256 * j;
            int row = q >> 3, kq = (q & 7) << 2;
            int v = m0 + row, k = k0 + kq;
            if (v < M && k < K)
                aR[j] = *reinterpret_cast<const float4*>(A + (size_t)v * K + k);
            else
                aR[j] = make_float4(0.f, 0.f, 0.f, 0.f);
        }
        #pragma unroll
        for (int j = 0; j < 2; ++j) {
            int q = tid + 256 * j;
            int krow = q >> 4, nq = (q & 15) << 2;
            int k = k0 + krow, n = n0 + nq;
            bR[2 * j]     = (k < K && n + 1 < N)
                ? *reinterpret_cast<const float2*>(B + (size_t)k * N + n)     : make_float2(0.f, 0.f);
            bR[2 * j + 1] = (k < K && n + 3 < N)
                ? *reinterpret_cast<const float2*>(B + (size_t)k * N + n + 2) : make_float2(0.f, 0.f);
        }
    };
    auto stage = [&]() {
        #pragma unroll
        for (int j = 0; j < 4; ++j) {
            int q = tid + 256 * j;
            int row = q >> 3, kq = (q & 7) << 2;
            As[kq + 0][row] = aR[j].x; As[kq + 1][row] = aR[j].y;
            As[kq + 2][row] = aR[j].z; As[kq + 3][row] = aR[j].w;
        }
        #pragma unroll
        for (int j = 0; j < 2; ++j) {
            int q = tid + 256 * j;
            int krow = q >> 4, nq = (q & 15) << 2;
            *reinterpret_cast<float2*>(&Bs[krow][nq])     = bR[2 * j];
            *reinterpret_cast<float2*>(&Bs[krow][nq + 2]) = bR[2 * j + 1];
        }
    };

    float acc[8][4];
    #pragma unroll
    for (int i = 0; i < 8; ++i)
        #pragma unroll
        for (int j = 0; j < 4; ++j) acc[i][j] = 0.f;

    load_tile(0);
    stage();
    __syncthreads();

    for (int kt = 0; kt < nkt; ++kt) {
        if (kt + 1 < nkt) load_tile(kt + 1);
        #pragma unroll 16
        for (int k = 0; k < 32; ++k) {
            float4 a0 = *reinterpret_cast<const float4*>(&As[k][ty * 8]);
            float4 a1 = *reinterpret_cast<const float4*>(&As[k][ty * 8 + 4]);
            float4 b  = *reinterpret_cast<const float4*>(&Bs[k][tx * 4]);
            float av[8] = {a0.x, a0.y, a0.z, a0.w, a1.x, a1.y, a1.z, a1.w};
            float bv[4] = {b.x, b.y, b.z, b.w};
            #pragma unroll
            for (int i = 0; i < 8; ++i)
                #pragma unroll
                for (int j = 0; j < 4; ++j)
                    acc[i][j] = fmaf(av[i], bv[j], acc[i][j]);
        }
        __syncthreads();
        if (kt + 1 < nkt) { stage(); __syncthreads(); }
    }

    #pragma unroll
    for (int i = 0; i < 8; ++i) {
        int vr = m0 + ty * 8 + i;
        if (vr >= M) continue;
        int nb = n0 + tx * 4;
        size_t base = (size_t)vr * N + nb;
        if (nb + 1 < N) {
            float2 o = {acc[i][0] + bias[nb], acc[i][1] + bias[nb + 1]};
            *reinterpret_cast<float2*>(C + base) = o;
        }
        if (nb + 3 < N) {
            float2 o = {acc[i][2] + bias[nb + 2], acc[i][3] + bias[nb + 3]};
            *reinterpret_cast<float2*>(C + base + 2) = o;
        }
    }
}

// ---------------------------------------------------------------------------
// AngularMaxPooling + BatchNorm. One wave per vertex. conv row stride = NP.
__global__ __launch_bounds__(256) void amp_bn(
    const float* __restrict__ conv,   // (MP, NP) layout [v][rot*100+t]
    const float* __restrict__ g,  const float* __restrict__ be,
    const float* __restrict__ mu, const float* __restrict__ var,
    float* __restrict__ xout)         // (VN, 100)
{
    int v = blockIdx.x * 4 + (threadIdx.x >> 6);
    int lane = threadIdx.x & 63;
    if (v >= VN) return;
    const float* y = conv + (size_t)v * NP;

    float s[8];
    #pragma unroll
    for (int n = 0; n < 8; ++n) {
        float t1 = y[n * TN + lane];
        float t2 = (lane < 36) ? y[n * TN + 64 + lane] : 0.f;
        s[n] = t1 * t1 + t2 * t2;
    }
    #pragma unroll
    for (int off = 32; off > 0; off >>= 1)
        #pragma unroll
        for (int n = 0; n < 8; ++n) s[n] += __shfl_xor(s[n], off);

    int best = 0; float bs = s[0];
    #pragma unroll
    for (int n = 1; n < 8; ++n) { if (s[n] > bs) { bs = s[n]; best = n; } }

    const float* yb = y + best * TN;
    for (int t = lane; t < TN; t += 64) {
        float inv = 1.0f / sqrtf(var[t] + 1e-3f);
        xout[v * TN + t] = g[t] * (yb[t] - mu[t]) * inv + be[t];
    }
}

// ---------------------------------------------------------------------------
// dense-head operand conversion (split bf16, padded to MP x 128)
__global__ __launch_bounds__(256) void dense_a_split(
    const float* __restrict__ xA, short* __restrict__ Ah, short* __restrict__ Al)
{
    int i = blockIdx.x * 256 + threadIdx.x;
    if (i >= MP * 128) return;
    int v = i >> 7, k = i & 127;
    float f = (v < VN && k < TN) ? xA[v * TN + k] : 0.f;
    short h, l; split_bf16(f, &h, &l);
    Ah[i] = h; Al[i] = l;
}
__global__ __launch_bounds__(256) void dense_b_split(
    const float* __restrict__ dw, short* __restrict__ Bh, short* __restrict__ Bl)
{
    int i = blockIdx.x * 256 + threadIdx.x;
    if (i >= MP * 128) return;
    int n = i >> 7, k = i & 127;
    float f = (n < VN && k < TN) ? dw[(size_t)k * VN + n] : 0.f;   // Bt[n][k] = dw[k][n]
    short h, l; split_bf16(f, &h, &l);
    Bh[i] = h; Bl[i] = l;
}

// ---------------------------------------------------------------------------
extern "C" void kernel_launch(void* const* d_in, const int* in_sizes, int n_in,
                              void* d_out, int out_size, void* d_ws, size_t ws_size,
                              hipStream_t stream) {
    const float* signal = (const float*)d_in[0];
    const int*   bcix   = (const int*)  d_in[1];
    const float* bcw    = (const float*)d_in[2];
    const float* nmean  = (const float*)d_in[3];
    const float* nvar   = (const float*)d_in[4];
    const float* w0     = (const float*)d_in[5];
    const float* b0     = (const float*)d_in[6];
    const float* w1     = (const float*)d_in[7];
    const float* b1     = (const float*)d_in[8];
    const float* w2     = (const float*)d_in[9];
    const float* b2     = (const float*)d_in[10];
    const float* bng    = (const float*)d_in[11];
    const float* bnb    = (const float*)d_in[12];
    const float* bnm    = (const float*)d_in[13];
    const float* bnv    = (const float*)d_in[14];
    const float* dw     = (const float*)d_in[15];
    const float* db     = (const float*)d_in[16];
    float* out = (float*)d_out;

    // workspace (>=5.6MB proven): small activations
    float* x0 = (float*)d_ws;
    float* xA = x0 + 20736;       // V*3 padded
    float* xB = xA + 689024;      // V*100 padded
    // dense-head split scratch overlaps xB (dead by dense time)
    short* dAh = (short*)xB;
    short* dAl = dAh + (size_t)MP * 128;
    short* dBh = dAl + (size_t)MP * 128;
    short* dBl = dBh + (size_t)MP * 128;
    const size_t ws_need = (size_t)709760 * 4 + (size_t)4 * MP * 128 * 2; // 9,916,928 B
    const bool dense_mfma = ws_size >= ws_need;

    // big scratch in d_out (V*V floats = 47.47M, dead until dense):
    // Ph/Pl: (MP x 4000) bf16 each; Bth/Btl: (NP x 4000) bf16 each; conv: (MP x NP) f32
    short* Ph  = (short*)out;
    short* Pl  = Ph  + (size_t)MP * 4000;
    short* Bth = Pl  + (size_t)MP * 4000;
    short* Btl = Bth + (size_t)NP * 4000;
    float* conv = out + (size_t)MP * 4000 + (size_t)NP * 4000;  // 31,232,000 floats in

    dim3 cgrid(MP / 128, NP / 128);        // 54 x 7
    dim3 mgrid(MP / 128, MP / 128);        // 54 x 54 (dense MFMA)
    dim3 dgrid((VN + 127) / 128, (VN + 63) / 64);   // fp32 fallback
    int ampg = (VN + 3) / 4;

    norm_kernel<<<(VN * 3 + 255) / 256, 256, 0, stream>>>(signal, nmean, nvar, x0);

    // layer 0 (CIN=3, K=120 -> padded 128)
    rotw_split<3, 128><<<NP, 256, 0, stream>>>(w0, Bth, Btl);
    patch_split<3, 128><<<MP, 256, 0, stream>>>(x0, bcix, bcw, Ph, Pl);
    mfma_gemm<true><<<cgrid, 256, 0, stream>>>(Ph, Pl, Bth, Btl, b0, conv, VN, NOUT, NP, 128);
    amp_bn<<<ampg, 256, 0, stream>>>(conv, bng, bnb, bnm, bnv, xA);

    // layer 1 (CIN=100, K=4000)
    rotw_split<100, 4000><<<NP, 256, 0, stream>>>(w1, Bth, Btl);
    patch_split<100, 4000><<<MP, 256, 0, stream>>>(xA, bcix, bcw, Ph, Pl);
    mfma_gemm<true><<<cgrid, 256, 0, stream>>>(Ph, Pl, Bth, Btl, b1, conv, VN, NOUT, NP, 4000);
    amp_bn<<<ampg, 256, 0, stream>>>(conv, bng + 100, bnb + 100, bnm + 100, bnv + 100, xB);

    // layer 2 (CIN=100, K=4000)
    rotw_split<100, 4000><<<NP, 256, 0, stream>>>(w2, Bth, Btl);
    patch_split<100, 4000><<<MP, 256, 0, stream>>>(xB, bcix, bcw, Ph, Pl);
    mfma_gemm<true><<<cgrid, 256, 0, stream>>>(Ph, Pl, Bth, Btl, b2, conv, VN, NOUT, NP, 4000);
    amp_bn<<<ampg, 256, 0, stream>>>(conv, bng + 200, bnb + 200, bnm + 200, bnv + 200, xA);

    // dense head (K=100 -> padded 128, N=V)
    if (dense_mfma) {
        dense_a_split<<<(MP * 128 + 255) / 256, 256, 0, stream>>>(xA, dAh, dAl);
        dense_b_split<<<(MP * 128 + 255) / 256, 256, 0, stream>>>(dw, dBh, dBl);
        mfma_gemm<false><<<mgrid, 256, 0, stream>>>(dAh, dAl, dBh, dBl, db, out, VN, VN, VN, 128);
    } else {
        tile_gemm<false><<<dgrid, 256, 0, stream>>>(xA, dw, db, out, VN, VN, TN);
    }
}

// Round 4
// 756.291 us; speedup vs baseline: 2.4482x; 1.0029x over previous
//
#include <hip/hip_runtime.h>

#define VN 6890
#define TN 100
#define NOUT 800   // 8 rotations * 100 templates
#define MP 6912    // VN padded to 54*128
#define NP 896     // NOUT padded to 7*128
#define CONVSZ (MP * NP)   // one split-K partial buffer (floats)

typedef __attribute__((ext_vector_type(8))) short bf16x8;
typedef __attribute__((ext_vector_type(4))) float f32x4;

// ---------------------------------------------------------------------------
// helpers
__device__ __forceinline__ unsigned short f2bf(float f) {
    unsigned u = __float_as_uint(f);
    return (unsigned short)((u + 0x7FFFu + ((u >> 16) & 1u)) >> 16);
}
__device__ __forceinline__ void split_bf16(float f, short* h, short* l) {
    unsigned short hb = f2bf(f);
    float hf = __uint_as_float(((unsigned)hb) << 16);
    *h = (short)hb;
    *l = (short)f2bf(f - hf);
}
__device__ __forceinline__ void gload16(const short* g, void* lds) {
    __builtin_amdgcn_global_load_lds(
        (const __attribute__((address_space(1))) void*)g,
        (__attribute__((address_space(3))) void*)lds, 16, 0, 0);
}

// ---------------------------------------------------------------------------
// x0[v,c] = (signal[v,c] - mean[c]) / sqrt(var[c])
__global__ __launch_bounds__(256) void norm_kernel(
    const float* __restrict__ sig, const float* __restrict__ mean,
    const float* __restrict__ var, float* __restrict__ x0)
{
    int i = blockIdx.x * blockDim.x + threadIdx.x;
    if (i < VN * 3) {
        int c = i % 3;
        x0[i] = (sig[i] - mean[c]) / sqrtf(var[c]);
    }
}

// ---------------------------------------------------------------------------
// Rotated weights, TRANSPOSED + split:  Bt[n][k] = W[t, r, (a+rot)&7, c]
// n = rot*100 + t (padded to NP with zeros), k = (r*8+a)*CIN + c (padded to KPAD).
template<int CIN, int KPAD>
__global__ __launch_bounds__(256) void rotw_split(
    const float* __restrict__ W, short* __restrict__ Bh, short* __restrict__ Bl)
{
    const int n = blockIdx.x;          // 0..NP-1
    const int K = 40 * CIN;
    const int rot = n / TN, t = n - rot * TN;
    for (int k = threadIdx.x; k < KPAD; k += 256) {
        float w = 0.f;
        if (n < NOUT && k < K) {
            int ra = k / CIN, c = k - ra * CIN;
            int r = ra >> 3, a = ra & 7;
            int a2 = (a + rot) & 7;
            w = W[((t * 5 + r) * 8 + a2) * CIN + c];
        }
        short h, l; split_bf16(w, &h, &l);
        Bh[(size_t)n * KPAD + k] = h;
        Bl[(size_t)n * KPAD + k] = l;
    }
}

// ---------------------------------------------------------------------------
// Barycentric patch, split to bf16 hi/lo:  P[v][ra*CIN+c], rows padded to MP.
template<int CIN, int KPAD>
__global__ __launch_bounds__(256) void patch_split(
    const float* __restrict__ x, const int* __restrict__ bidx,
    const float* __restrict__ bw, short* __restrict__ Ph, short* __restrict__ Pl)
{
    __shared__ int   sIdx[120];
    __shared__ float sW[120];
    const int v = blockIdx.x;
    const int tid = threadIdx.x;
    const int K = 40 * CIN;
    if (v >= VN) {   // zero-pad rows (block-uniform branch)
        for (int e = tid; e < KPAD; e += 256) {
            Ph[(size_t)v * KPAD + e] = 0;
            Pl[(size_t)v * KPAD + e] = 0;
        }
        return;
    }
    if (tid < 120) { sIdx[tid] = bidx[v * 120 + tid]; sW[tid] = bw[v * 120 + tid]; }
    __syncthreads();
    for (int e = tid; e < KPAD; e += 256) {
        float s = 0.f;
        if (e < K) {
            int ra = e / CIN, c = e - ra * CIN;
            s = sW[ra * 3 + 0] * x[sIdx[ra * 3 + 0] * CIN + c]
              + sW[ra * 3 + 1] * x[sIdx[ra * 3 + 1] * CIN + c]
              + sW[ra * 3 + 2] * x[sIdx[ra * 3 + 2] * CIN + c];
        }
        short h, l; split_bf16(s, &h, &l);
        Ph[(size_t)v * KPAD + e] = h;
        Pl[(size_t)v * KPAD + e] = l;
    }
}

// ---------------------------------------------------------------------------
// Split-bf16 MFMA GEMM:  C = A @ B^T  with A=(Ah+Al), B^T rows=(Bh+Bl), both (rows x K)
// 3-product Markidis: acc = Ah·Bh + Ah·Bl + Al·Bh  (fp32 MFMA accumulate).
// 128x128 tile, BK=32, 256 threads (4 waves, 2x2), 4x4 16x16x32 frags per wave.
// Split-K over blockIdx.z: slice z covers [z*Ksl, min(K, (z+1)*Ksl)).
// *** Ksl must be a multiple of 32; the tail slice length kcnt = min(Ksl, K - z*Ksl)
// *** must also be a multiple of 32 (K % 32 == 0).
// CONV_EPI: RAW partial store (bias/relu deferred to amp_bn), C += z*cstride,
//           no guards (C is MP x NP scratch).
// else:     bias[n], no relu, guarded stores (C is the real out, ldc=N=VN), z==0.
template<bool CONV_EPI>
__global__ __launch_bounds__(256, 2) void mfma_gemm(
    const short* __restrict__ Ah, const short* __restrict__ Al,
    const short* __restrict__ Bh, const short* __restrict__ Bl,
    const float* __restrict__ bias, float* __restrict__ C,
    int M, int N, int ldc, int K, int Ksl, int cstride)
{
    __shared__ __align__(16) short AhS[4096];   // 128 rows x 32 bf16 (64B rows)
    __shared__ __align__(16) short AlS[4096];
    __shared__ __align__(16) short BhS[4096];
    __shared__ __align__(16) short BlS[4096];

    const int tid  = threadIdx.x;
    const int wave = tid >> 6;
    const int lane = tid & 63;
    const int lr = lane & 15, lg = lane >> 4;
    const int wm = wave >> 1, wn = wave & 1;
    const int m0 = blockIdx.x * 128;
    const int n0 = blockIdx.y * 128;
    const int kbase = blockIdx.z * Ksl;
    const int kcnt  = min(Ksl, K - kbase);   // 63/62-tile asymmetric slices ok
    if (CONV_EPI) C += (size_t)blockIdx.z * cstride;

    // staging source offsets (inverse-swizzled): LDS byte off = row*64 + p*16,
    // physical chunk p holds logical k-chunk g = p ^ ((row>>1)&3)
    const int off0 = tid * 16, off1 = off0 + 4096;
    const int row0 = off0 >> 6, row1 = off1 >> 6;
    const int g0 = ((off0 >> 4) & 3) ^ ((row0 >> 1) & 3);
    const int g1 = ((off1 >> 4) & 3) ^ ((row1 >> 1) & 3);
    const size_t aO0 = (size_t)(m0 + row0) * K + kbase + g0 * 8;
    const size_t aO1 = (size_t)(m0 + row1) * K + kbase + g1 * 8;
    const size_t bO0 = (size_t)(n0 + row0) * K + kbase + g0 * 8;
    const size_t bO1 = (size_t)(n0 + row1) * K + kbase + g1 * 8;
    const int wofs = wave << 10;

    // swizzled ds_read byte offsets (loop-invariant)
    int aRd[4], bRd[4];
    #pragma unroll
    for (int f = 0; f < 4; ++f) {
        int ar = wm * 64 + f * 16 + lr;
        aRd[f] = ar * 64 + ((lg ^ ((ar >> 1) & 3)) << 4);
        int br = wn * 64 + f * 16 + lr;
        bRd[f] = br * 64 + ((lg ^ ((br >> 1) & 3)) << 4);
    }

    f32x4 acc[4][4];
    #pragma unroll
    for (int i = 0; i < 4; ++i)
        #pragma unroll
        for (int j = 0; j < 4; ++j)
            acc[i][j] = (f32x4){0.f, 0.f, 0.f, 0.f};

    const int nkt = kcnt >> 5;
    for (int kt = 0; kt < nkt; ++kt) {
        const int k0 = kt << 5;
        gload16(Ah + aO0 + k0, (char*)AhS + wofs);
        gload16(Ah + aO1 + k0, (char*)AhS + 4096 + wofs);
        gload16(Al + aO0 + k0, (char*)AlS + wofs);
        gload16(Al + aO1 + k0, (char*)AlS + 4096 + wofs);
        gload16(Bh + bO0 + k0, (char*)BhS + wofs);
        gload16(Bh + bO1 + k0, (char*)BhS + 4096 + wofs);
        gload16(Bl + bO0 + k0, (char*)BlS + wofs);
        gload16(Bl + bO1 + k0, (char*)BlS + 4096 + wofs);
        __syncthreads();   // compiler drains vmcnt(0) before s_barrier

        bf16x8 ah[4], al[4], bh[4], bl[4];
        #pragma unroll
        for (int f = 0; f < 4; ++f) {
            ah[f] = *(const bf16x8*)((const char*)AhS + aRd[f]);
            al[f] = *(const bf16x8*)((const char*)AlS + aRd[f]);
            bh[f] = *(const bf16x8*)((const char*)BhS + bRd[f]);
            bl[f] = *(const bf16x8*)((const char*)BlS + bRd[f]);
        }
        #pragma unroll
        for (int i = 0; i < 4; ++i)
            #pragma unroll
            for (int j = 0; j < 4; ++j)
                acc[i][j] = __builtin_amdgcn_mfma_f32_16x16x32_bf16(ah[i], bh[j], acc[i][j], 0, 0, 0);
        #pragma unroll
        for (int i = 0; i < 4; ++i)
            #pragma unroll
            for (int j = 0; j < 4; ++j)
                acc[i][j] = __builtin_amdgcn_mfma_f32_16x16x32_bf16(ah[i], bl[j], acc[i][j], 0, 0, 0);
        #pragma unroll
        for (int i = 0; i < 4; ++i)
            #pragma unroll
            for (int j = 0; j < 4; ++j)
                acc[i][j] = __builtin_amdgcn_mfma_f32_16x16x32_bf16(al[i], bh[j], acc[i][j], 0, 0, 0);
        __syncthreads();
    }

    // epilogue: D row = lg*4+q, col = lr  (m89-verified C/D layout)
    #pragma unroll
    for (int i = 0; i < 4; ++i) {
        const int mb = m0 + wm * 64 + i * 16 + lg * 4;
        #pragma unroll
        for (int j = 0; j < 4; ++j) {
            const int n = n0 + wn * 64 + j * 16 + lr;
            if (CONV_EPI) {
                #pragma unroll
                for (int q = 0; q < 4; ++q)
                    C[(size_t)(mb + q) * ldc + n] = acc[i][j][q];
            } else {
                if (n < N) {
                    const float bv = bias[n];
                    #pragma unroll
                    for (int q = 0; q < 4; ++q)
                        if (mb + q < M)
                            C[(size_t)(mb + q) * ldc + n] = acc[i][j][q] + bv;
                }
            }
        }
    }
}

// ---------------------------------------------------------------------------
// fp32 fallback SGEMM for the dense head (used only if workspace is too small
// for the split-bf16 dense scratch).
template<bool CONV_EPI>
__global__ __launch_bounds__(256, 4) void tile_gemm(
    const float* __restrict__ A, const float* __restrict__ B,
    const float* __restrict__ bias, float* __restrict__ C,
    int M, int N, int K)
{
    __shared__ __align__(16) float As[32][132];
    __shared__ __align__(16) float Bs[32][68];

    const int tid = threadIdx.x;
    const int m0 = blockIdx.x * 128;
    const int n0 = blockIdx.y * 64;
    const int ty = tid >> 4;
    const int tx = tid & 15;
    const int nkt = (K + 31) >> 5;

    float4 aR[4];
    float2 bR[4];

    auto load_tile = [&](int kt) {
        const int k0 = kt << 5;
        #pragma unroll
        for (int j = 0; j < 4; ++j) {
            int q = tid + 256 * j;
            int row = q >> 3, kq = (q & 7) << 2;
            int v = m0 + row, k = k0 + kq;
            if (v < M && k < K)
                aR[j] = *reinterpret_cast<const float4*>(A + (size_t)v * K + k);
            else
                aR[j] = make_float4(0.f, 0.f, 0.f, 0.f);
        }
        #pragma unroll
        for (int j = 0; j < 2; ++j) {
            int q = tid + 256 * j;
            int krow = q >> 4, nq = (q & 15) << 2;
            int k = k0 + krow, n = n0 + nq;
            bR[2 * j]     = (k < K && n + 1 < N)
                ? *reinterpret_cast<const float2*>(B + (size_t)k * N + n)     : make_float2(0.f, 0.f);
            bR[2 * j + 1] = (k < K && n + 3 < N)
                ? *reinterpret_cast<const float2*>(B + (size_t)k * N + n + 2) : make_float2(0.f, 0.f);
        }
    };
    auto stage = [&]() {
        #pragma unroll
        for (int j = 0; j < 4; ++j) {
            int q = tid + 256 * j;
            int row = q >> 3, kq = (q & 7) << 2;
            As[kq + 0][row] = aR[j].x; As[kq + 1][row] = aR[j].y;
            As[kq + 2][row] = aR[j].z; As[kq + 3][row] = aR[j].w;
        }
        #pragma unroll
        for (int j = 0; j < 2; ++j) {
            int q = tid + 256 * j;
            int krow = q >> 4, nq = (q & 15) << 2;
            *reinterpret_cast<float2*>(&Bs[krow][nq])     = bR[2 * j];
            *reinterpret_cast<float2*>(&Bs[krow][nq + 2]) = bR[2 * j + 1];
        }
    };

    float acc[8][4];
    #pragma unroll
    for (int i = 0; i < 8; ++i)
        #pragma unroll
        for (int j = 0; j < 4; ++j) acc[i][j] = 0.f;

    load_tile(0);
    stage();
    __syncthreads();

    for (int kt = 0; kt < nkt; ++kt) {
        if (kt + 1 < nkt) load_tile(kt + 1);
        #pragma unroll 16
        for (int k = 0; k < 32; ++k) {
            float4 a0 = *reinterpret_cast<const float4*>(&As[k][ty * 8]);
            float4 a1 = *reinterpret_cast<const float4*>(&As[k][ty * 8 + 4]);
            float4 b  = *reinterpret_cast<const float4*>(&Bs[k][tx * 4]);
            float av[8] = {a0.x, a0.y, a0.z, a0.w, a1.x, a1.y, a1.z, a1.w};
            float bv[4] = {b.x, b.y, b.z, b.w};
            #pragma unroll
            for (int i = 0; i < 8; ++i)
                #pragma unroll
                for (int j = 0; j < 4; ++j)
                    acc[i][j] = fmaf(av[i], bv[j], acc[i][j]);
        }
        __syncthreads();
        if (kt + 1 < nkt) { stage(); __syncthreads(); }
    }

    #pragma unroll
    for (int i = 0; i < 8; ++i) {
        int vr = m0 + ty * 8 + i;
        if (vr >= M) continue;
        int nb = n0 + tx * 4;
        size_t base = (size_t)vr * N + nb;
        if (nb + 1 < N) {
            float2 o = {acc[i][0] + bias[nb], acc[i][1] + bias[nb + 1]};
            *reinterpret_cast<float2*>(C + base) = o;
        }
        if (nb + 3 < N) {
            float2 o = {acc[i][2] + bias[nb + 2], acc[i][3] + bias[nb + 3]};
            *reinterpret_cast<float2*>(C + base + 2) = o;
        }
    }
}

// ---------------------------------------------------------------------------
// Split-K reduce + bias + relu + AngularMaxPooling + BatchNorm.
// One wave per vertex; entire 800-vector kept in registers (no re-read).
__global__ __launch_bounds__(256) void amp_bn(
    const float* __restrict__ conv,   // 2 partial buffers (MP, NP), CONVSZ apart
    const float* __restrict__ bias,   // conv bias (TN), applied post-reduction
    const float* __restrict__ g,  const float* __restrict__ be,
    const float* __restrict__ mu, const float* __restrict__ var,
    float* __restrict__ xout)         // (VN, 100)
{
    int v = blockIdx.x * 4 + (threadIdx.x >> 6);
    int lane = threadIdx.x & 63;
    if (v >= VN) return;
    const float* y0 = conv + (size_t)v * NP;
    const float* y1 = y0 + CONVSZ;

    const float bLo = bias[lane];
    const float bHi = (lane < 36) ? bias[64 + lane] : 0.f;

    float t1[8], t2[8], s[8];
    #pragma unroll
    for (int n = 0; n < 8; ++n) {
        float a = fmaxf(y0[n * TN + lane] + y1[n * TN + lane] + bLo, 0.f);
        float b = (lane < 36)
            ? fmaxf(y0[n * TN + 64 + lane] + y1[n * TN + 64 + lane] + bHi, 0.f) : 0.f;
        t1[n] = a; t2[n] = b;
        s[n] = a * a + b * b;
    }
    #pragma unroll
    for (int off = 32; off > 0; off >>= 1)
        #pragma unroll
        for (int n = 0; n < 8; ++n) s[n] += __shfl_xor(s[n], off);

    int best = 0; float bs = s[0];
    #pragma unroll
    for (int n = 1; n < 8; ++n) { if (s[n] > bs) { bs = s[n]; best = n; } }

    // static-index select of the winning rotation (avoids scratch, rule #20)
    float a = t1[0], b = t2[0];
    #pragma unroll
    for (int n = 1; n < 8; ++n) { if (best == n) { a = t1[n]; b = t2[n]; } }

    {
        float inv = 1.0f / sqrtf(var[lane] + 1e-3f);
        xout[v * TN + lane] = g[lane] * (a - mu[lane]) * inv + be[lane];
    }
    if (lane < 36) {
        int t = 64 + lane;
        float inv = 1.0f / sqrtf(var[t] + 1e-3f);
        xout[v * TN + t] = g[t] * (b - mu[t]) * inv + be[t];
    }
}

// ---------------------------------------------------------------------------
// dense-head operand conversion (split bf16, padded to MP x 128)
__global__ __launch_bounds__(256) void dense_a_split(
    const float* __restrict__ xA, short* __restrict__ Ah, short* __restrict__ Al)
{
    int i = blockIdx.x * 256 + threadIdx.x;
    if (i >= MP * 128) return;
    int v = i >> 7, k = i & 127;
    float f = (v < VN && k < TN) ? xA[v * TN + k] : 0.f;
    short h, l; split_bf16(f, &h, &l);
    Ah[i] = h; Al[i] = l;
}
__global__ __launch_bounds__(256) void dense_b_split(
    const float* __restrict__ dw, short* __restrict__ Bh, short* __restrict__ Bl)
{
    int i = blockIdx.x * 256 + threadIdx.x;
    if (i >= MP * 128) return;
    int n = i >> 7, k = i & 127;
    float f = (n < VN && k < TN) ? dw[(size_t)k * VN + n] : 0.f;   // Bt[n][k] = dw[k][n]
    short h, l; split_bf16(f, &h, &l);
    Bh[i] = h; Bl[i] = l;
}

// ---------------------------------------------------------------------------
extern "C" void kernel_launch(void* const* d_in, const int* in_sizes, int n_in,
                              void* d_out, int out_size, void* d_ws, size_t ws_size,
                              hipStream_t stream) {
    const float* signal = (const float*)d_in[0];
    const int*   bcix   = (const int*)  d_in[1];
    const float* bcw    = (const float*)d_in[2];
    const float* nmean  = (const float*)d_in[3];
    const float* nvar   = (const float*)d_in[4];
    const float* w0     = (const float*)d_in[5];
    const float* b0     = (const float*)d_in[6];
    const float* w1     = (const float*)d_in[7];
    const float* b1     = (const float*)d_in[8];
    const float* w2     = (const float*)d_in[9];
    const float* b2     = (const float*)d_in[10];
    const float* bng    = (const float*)d_in[11];
    const float* bnb    = (const float*)d_in[12];
    const float* bnm    = (const float*)d_in[13];
    const float* bnv    = (const float*)d_in[14];
    const float* dw     = (const float*)d_in[15];
    const float* db     = (const float*)d_in[16];
    float* out = (float*)d_out;

    // workspace: small activations
    float* x0 = (float*)d_ws;
    float* xA = x0 + 20736;       // V*3 padded
    float* xB = xA + 689024;      // V*100 padded
    // dense-head split scratch overlaps xB (dead by dense time)
    short* dAh = (short*)xB;
    short* dAl = dAh + (size_t)MP * 128;
    short* dBh = dAl + (size_t)MP * 128;
    short* dBl = dBh + (size_t)MP * 128;
    const size_t ws_need = (size_t)709760 * 4 + (size_t)4 * MP * 128 * 2; // 9,916,928 B
    const bool dense_mfma = ws_size >= ws_need;

    // big scratch in d_out (V*V floats = 47.47M, dead until dense):
    // Ph/Pl: (MP x 4000) bf16; Bth/Btl: (NP x 4000) bf16; conv: 2 x (MP x NP) f32
    short* Ph  = (short*)out;
    short* Pl  = Ph  + (size_t)MP * 4000;
    short* Bth = Pl  + (size_t)MP * 4000;
    short* Btl = Bth + (size_t)NP * 4000;
    float* conv = out + (size_t)MP * 4000 + (size_t)NP * 4000;  // 31,232,000 floats in
    // conv uses 2*CONVSZ = 12,386,304 floats -> ends at 43.6M < 47.47M ok

    dim3 cgrid(MP / 128, NP / 128, 2);     // 54 x 7 x 2 (split-K) = 756 blocks
    dim3 mgrid(MP / 128, MP / 128, 1);     // 54 x 54 (dense MFMA)
    dim3 dgrid((VN + 127) / 128, (VN + 63) / 64);   // fp32 fallback
    int ampg = (VN + 3) / 4;

    norm_kernel<<<(VN * 3 + 255) / 256, 256, 0, stream>>>(signal, nmean, nvar, x0);

    // layer 0 (CIN=3, K=120 -> padded 128, split-K 64+64)
    rotw_split<3, 128><<<NP, 256, 0, stream>>>(w0, Bth, Btl);
    patch_split<3, 128><<<MP, 256, 0, stream>>>(x0, bcix, bcw, Ph, Pl);
    mfma_gemm<true><<<cgrid, 256, 0, stream>>>(Ph, Pl, Bth, Btl, b0, conv, VN, NOUT, NP, 128, 64, CONVSZ);
    amp_bn<<<ampg, 256, 0, stream>>>(conv, b0, bng, bnb, bnm, bnv, xA);

    // layer 1 (CIN=100, K=4000, split-K 2016+1984 -- both %32==0)
    rotw_split<100, 4000><<<NP, 256, 0, stream>>>(w1, Bth, Btl);
    patch_split<100, 4000><<<MP, 256, 0, stream>>>(xA, bcix, bcw, Ph, Pl);
    mfma_gemm<true><<<cgrid, 256, 0, stream>>>(Ph, Pl, Bth, Btl, b1, conv, VN, NOUT, NP, 4000, 2016, CONVSZ);
    amp_bn<<<ampg, 256, 0, stream>>>(conv, b1, bng + 100, bnb + 100, bnm + 100, bnv + 100, xB);

    // layer 2 (CIN=100, K=4000, split-K 2016+1984)
    rotw_split<100, 4000><<<NP, 256, 0, stream>>>(w2, Bth, Btl);
    patch_split<100, 4000><<<MP, 256, 0, stream>>>(xB, bcix, bcw, Ph, Pl);
    mfma_gemm<true><<<cgrid, 256, 0, stream>>>(Ph, Pl, Bth, Btl, b2, conv, VN, NOUT, NP, 4000, 2016, CONVSZ);
    amp_bn<<<ampg, 256, 0, stream>>>(conv, b2, bng + 200, bnb + 200, bnm + 200, bnv + 200, xA);

    // dense head (K=100 -> padded 128, N=V)
    if (dense_mfma) {
        dense_a_split<<<(MP * 128 + 255) / 256, 256, 0, stream>>>(xA, dAh, dAl);
        dense_b_split<<<(MP * 128 + 255) / 256, 256, 0, stream>>>(dw, dBh, dBl);
        mfma_gemm<false><<<mgrid, 256, 0, stream>>>(dAh, dAl, dBh, dBl, db, out, VN, VN, VN, 128, 128, 0);
    } else {
        tile_gemm<false><<<dgrid, 256, 0, stream>>>(xA, dw, db, out, VN, VN, TN);
    }
}

// Round 5
// 742.278 us; speedup vs baseline: 2.4944x; 1.0189x over previous
//
#include <hip/hip_runtime.h>

#define VN 6890
#define TN 100
#define NOUT 800   // 8 rotations * 100 templates
#define MP 6912    // VN padded to 54*128
#define NP 896     // NOUT padded to 7*128
#define CONVSZ (MP * NP)   // one split-K partial buffer (floats)

typedef __attribute__((ext_vector_type(8))) short bf16x8;
typedef __attribute__((ext_vector_type(4))) float f32x4;

#define BAR() do { asm volatile("" ::: "memory"); __builtin_amdgcn_s_barrier(); asm volatile("" ::: "memory"); } while (0)

// ---------------------------------------------------------------------------
// helpers
__device__ __forceinline__ unsigned short f2bf(float f) {
    unsigned u = __float_as_uint(f);
    return (unsigned short)((u + 0x7FFFu + ((u >> 16) & 1u)) >> 16);
}
__device__ __forceinline__ void split_bf16(float f, short* h, short* l) {
    unsigned short hb = f2bf(f);
    float hf = __uint_as_float(((unsigned)hb) << 16);
    *h = (short)hb;
    *l = (short)f2bf(f - hf);
}
__device__ __forceinline__ void gload16(const short* g, void* lds) {
    __builtin_amdgcn_global_load_lds(
        (const __attribute__((address_space(1))) void*)g,
        (__attribute__((address_space(3))) void*)lds, 16, 0, 0);
}

// ---------------------------------------------------------------------------
__global__ __launch_bounds__(256) void norm_kernel(
    const float* __restrict__ sig, const float* __restrict__ mean,
    const float* __restrict__ var, float* __restrict__ x0)
{
    int i = blockIdx.x * blockDim.x + threadIdx.x;
    if (i < VN * 3) {
        int c = i % 3;
        x0[i] = (sig[i] - mean[c]) / sqrtf(var[c]);
    }
}

// ---------------------------------------------------------------------------
// Rotated weights, TRANSPOSED + split:  Bt[n][k] = W[t, r, (a+rot)&7, c]
template<int CIN, int KPAD>
__global__ __launch_bounds__(256) void rotw_split(
    const float* __restrict__ W, short* __restrict__ Bh, short* __restrict__ Bl)
{
    const int n = blockIdx.x;          // 0..NP-1
    const int K = 40 * CIN;
    const int rot = n / TN, t = n - rot * TN;
    for (int k = threadIdx.x; k < KPAD; k += 256) {
        float w = 0.f;
        if (n < NOUT && k < K) {
            int ra = k / CIN, c = k - ra * CIN;
            int r = ra >> 3, a = ra & 7;
            int a2 = (a + rot) & 7;
            w = W[((t * 5 + r) * 8 + a2) * CIN + c];
        }
        short h, l; split_bf16(w, &h, &l);
        Bh[(size_t)n * KPAD + k] = h;
        Bl[(size_t)n * KPAD + k] = l;
    }
}

// ---------------------------------------------------------------------------
// Barycentric patch, split to bf16 hi/lo:  P[v][ra*CIN+c], rows padded to MP.
template<int CIN, int KPAD>
__global__ __launch_bounds__(256) void patch_split(
    const float* __restrict__ x, const int* __restrict__ bidx,
    const float* __restrict__ bw, short* __restrict__ Ph, short* __restrict__ Pl)
{
    __shared__ int   sIdx[120];
    __shared__ float sW[120];
    const int v = blockIdx.x;
    const int tid = threadIdx.x;
    const int K = 40 * CIN;
    if (v >= VN) {
        for (int e = tid; e < KPAD; e += 256) {
            Ph[(size_t)v * KPAD + e] = 0;
            Pl[(size_t)v * KPAD + e] = 0;
        }
        return;
    }
    if (tid < 120) { sIdx[tid] = bidx[v * 120 + tid]; sW[tid] = bw[v * 120 + tid]; }
    __syncthreads();
    for (int e = tid; e < KPAD; e += 256) {
        float s = 0.f;
        if (e < K) {
            int ra = e / CIN, c = e - ra * CIN;
            s = sW[ra * 3 + 0] * x[sIdx[ra * 3 + 0] * CIN + c]
              + sW[ra * 3 + 1] * x[sIdx[ra * 3 + 1] * CIN + c]
              + sW[ra * 3 + 2] * x[sIdx[ra * 3 + 2] * CIN + c];
        }
        short h, l; split_bf16(s, &h, &l);
        Ph[(size_t)v * KPAD + e] = h;
        Pl[(size_t)v * KPAD + e] = l;
    }
}

// ---------------------------------------------------------------------------
// PROVEN 2-barrier split-bf16 MFMA GEMM (round-4 kernel). Used for layer 0
// (short K) and the dense head. 128x128 tile, 4 waves, BK=32.
template<bool CONV_EPI>
__global__ __launch_bounds__(256, 2) void mfma_gemm(
    const short* __restrict__ Ah, const short* __restrict__ Al,
    const short* __restrict__ Bh, const short* __restrict__ Bl,
    const float* __restrict__ bias, float* __restrict__ C,
    int M, int N, int ldc, int K, int Ksl, int cstride)
{
    __shared__ __align__(16) short AhS[4096];
    __shared__ __align__(16) short AlS[4096];
    __shared__ __align__(16) short BhS[4096];
    __shared__ __align__(16) short BlS[4096];

    const int tid  = threadIdx.x;
    const int wave = tid >> 6;
    const int lane = tid & 63;
    const int lr = lane & 15, lg = lane >> 4;
    const int wm = wave >> 1, wn = wave & 1;
    const int m0 = blockIdx.x * 128;
    const int n0 = blockIdx.y * 128;
    const int kbase = blockIdx.z * Ksl;
    const int kcnt  = min(Ksl, K - kbase);
    if (CONV_EPI) C += (size_t)blockIdx.z * cstride;

    const int off0 = tid * 16, off1 = off0 + 4096;
    const int row0 = off0 >> 6, row1 = off1 >> 6;
    const int g0 = ((off0 >> 4) & 3) ^ ((row0 >> 1) & 3);
    const int g1 = ((off1 >> 4) & 3) ^ ((row1 >> 1) & 3);
    const size_t aO0 = (size_t)(m0 + row0) * K + kbase + g0 * 8;
    const size_t aO1 = (size_t)(m0 + row1) * K + kbase + g1 * 8;
    const size_t bO0 = (size_t)(n0 + row0) * K + kbase + g0 * 8;
    const size_t bO1 = (size_t)(n0 + row1) * K + kbase + g1 * 8;
    const int wofs = wave << 10;

    int aRd[4], bRd[4];
    #pragma unroll
    for (int f = 0; f < 4; ++f) {
        int ar = wm * 64 + f * 16 + lr;
        aRd[f] = ar * 64 + ((lg ^ ((ar >> 1) & 3)) << 4);
        int br = wn * 64 + f * 16 + lr;
        bRd[f] = br * 64 + ((lg ^ ((br >> 1) & 3)) << 4);
    }

    f32x4 acc[4][4];
    #pragma unroll
    for (int i = 0; i < 4; ++i)
        #pragma unroll
        for (int j = 0; j < 4; ++j)
            acc[i][j] = (f32x4){0.f, 0.f, 0.f, 0.f};

    const int nkt = kcnt >> 5;
    for (int kt = 0; kt < nkt; ++kt) {
        const int k0 = kt << 5;
        gload16(Ah + aO0 + k0, (char*)AhS + wofs);
        gload16(Ah + aO1 + k0, (char*)AhS + 4096 + wofs);
        gload16(Al + aO0 + k0, (char*)AlS + wofs);
        gload16(Al + aO1 + k0, (char*)AlS + 4096 + wofs);
        gload16(Bh + bO0 + k0, (char*)BhS + wofs);
        gload16(Bh + bO1 + k0, (char*)BhS + 4096 + wofs);
        gload16(Bl + bO0 + k0, (char*)BlS + wofs);
        gload16(Bl + bO1 + k0, (char*)BlS + 4096 + wofs);
        __syncthreads();

        bf16x8 ah[4], al[4], bh[4], bl[4];
        #pragma unroll
        for (int f = 0; f < 4; ++f) {
            ah[f] = *(const bf16x8*)((const char*)AhS + aRd[f]);
            al[f] = *(const bf16x8*)((const char*)AlS + aRd[f]);
            bh[f] = *(const bf16x8*)((const char*)BhS + bRd[f]);
            bl[f] = *(const bf16x8*)((const char*)BlS + bRd[f]);
        }
        #pragma unroll
        for (int i = 0; i < 4; ++i)
            #pragma unroll
            for (int j = 0; j < 4; ++j)
                acc[i][j] = __builtin_amdgcn_mfma_f32_16x16x32_bf16(ah[i], bh[j], acc[i][j], 0, 0, 0);
        #pragma unroll
        for (int i = 0; i < 4; ++i)
            #pragma unroll
            for (int j = 0; j < 4; ++j)
                acc[i][j] = __builtin_amdgcn_mfma_f32_16x16x32_bf16(ah[i], bl[j], acc[i][j], 0, 0, 0);
        #pragma unroll
        for (int i = 0; i < 4; ++i)
            #pragma unroll
            for (int j = 0; j < 4; ++j)
                acc[i][j] = __builtin_amdgcn_mfma_f32_16x16x32_bf16(al[i], bh[j], acc[i][j], 0, 0, 0);
        __syncthreads();
    }

    #pragma unroll
    for (int i = 0; i < 4; ++i) {
        const int mb = m0 + wm * 64 + i * 16 + lg * 4;
        #pragma unroll
        for (int j = 0; j < 4; ++j) {
            const int n = n0 + wn * 64 + j * 16 + lr;
            if (CONV_EPI) {
                #pragma unroll
                for (int q = 0; q < 4; ++q)
                    C[(size_t)(mb + q) * ldc + n] = acc[i][j][q];
            } else {
                if (n < N) {
                    const float bv = bias[n];
                    #pragma unroll
                    for (int q = 0; q < 4; ++q)
                        if (mb + q < M)
                            C[(size_t)(mb + q) * ldc + n] = acc[i][j][q] + bv;
                }
            }
        }
    }
}

// ---------------------------------------------------------------------------
// NEW: 8-wave phase-interleaved split-bf16 MFMA GEMM (layers 1/2).
// 128x128 tile, BK=32, 512 threads (8 waves 2Mx4N, per-wave 64x32 out).
// Triple-buffered LDS (3 bufs x 4 regions x 8KB = 96 KiB), prefetch dist 2.
// 3 phases per K-tile (one per Markidis product pass); counted vmcnt(6) once
// per K-tile (never 0 in main loop); raw s_barrier; setprio around MFMA.
// vmcnt ledger: after p0-wait of tile t, outstanding <= 6 = [t+1:4, t+2:2];
// p1/p2 each issue 1 -> 8; next p0 issues 2 -> 10; vmcnt(6) retires tile
// t+1's 4 oldest. Tails: vmcnt(4) at t=nt-2, vmcnt(0) at t=nt-1.
// WAR: region written for tile t+2 was last read in tile t-1 whose reads
// complete before its phase's MFMA (lgkm) + trailing barrier. Requires nt>=2.
__global__ __launch_bounds__(512, 1) void mfma_conv512(
    const short* __restrict__ Ah, const short* __restrict__ Al,
    const short* __restrict__ Bh, const short* __restrict__ Bl,
    float* __restrict__ C, int K, int Ksl, int cstride)
{
    __shared__ __align__(16) short LDS[3 * 4 * 4096];   // 96 KiB

    const int tid = threadIdx.x;
    const int w = tid >> 6, lane = tid & 63;
    const int lr = lane & 15, lg = lane >> 4;
    const int wm = w >> 2, wn = w & 3;                 // 2 x 4 wave grid
    const int m0 = blockIdx.x * 128;
    const int n0 = blockIdx.y * 128;
    const int kbase = blockIdx.z * Ksl;
    const int kcnt = min(Ksl, K - kbase);
    C += (size_t)blockIdx.z * cstride;

    // staging source (inverse-swizzled): 512 threads cover one 8KB region
    const int srow = tid >> 2;                          // 0..127
    const int sg   = (tid & 3) ^ ((srow >> 1) & 3);
    const size_t aO = (size_t)(m0 + srow) * K + kbase + sg * 8;
    const size_t bO = (size_t)(n0 + srow) * K + kbase + sg * 8;
    const int wdst = w << 9;                            // wave dest offset (shorts)

    // ds_read byte offsets within a region (row stride 64B, XOR swizzle)
    int aRd[4], bRd[2];
    #pragma unroll
    for (int i = 0; i < 4; ++i) {
        int ar = wm * 64 + i * 16 + lr;
        aRd[i] = ar * 64 + ((lg ^ ((ar >> 1) & 3)) << 4);
    }
    #pragma unroll
    for (int j = 0; j < 2; ++j) {
        int br = wn * 32 + j * 16 + lr;
        bRd[j] = br * 64 + ((lg ^ ((br >> 1) & 3)) << 4);
    }

    f32x4 acc[4][2];
    #pragma unroll
    for (int i = 0; i < 4; ++i)
        #pragma unroll
        for (int j = 0; j < 2; ++j)
            acc[i][j] = (f32x4){0.f, 0.f, 0.f, 0.f};

    const int nt = kcnt >> 5;

    // region base (shorts): buf b, region r
    auto REG = [&](int b, int r) -> short* { return &LDS[(b * 4 + r) * 4096]; };

    // prologue: stage tiles 0 and 1 fully
    {
        gload16(Ah + aO,      REG(0, 0) + wdst);
        gload16(Al + aO,      REG(0, 1) + wdst);
        gload16(Bh + bO,      REG(0, 2) + wdst);
        gload16(Bl + bO,      REG(0, 3) + wdst);
        if (nt > 1) {
            gload16(Ah + aO + 32, REG(1, 0) + wdst);
            gload16(Al + aO + 32, REG(1, 1) + wdst);
            gload16(Bh + bO + 32, REG(1, 2) + wdst);
            gload16(Bl + bO + 32, REG(1, 3) + wdst);
        }
    }

    int cur = 0;
    for (int t = 0; t < nt; ++t) {
        const char* LAh = (const char*)REG(cur, 0);
        const char* LAl = (const char*)REG(cur, 1);
        const char* LBh = (const char*)REG(cur, 2);
        const char* LBl = (const char*)REG(cur, 3);
        const int nb = (t + 2) % 3;
        const int kn = (t + 2) << 5;

        // ---------- phase 0: stage Ah,Bh(t+2); counted wait; ah*bh ----------
        if (t + 2 < nt) {
            gload16(Ah + aO + kn, REG(nb, 0) + wdst);
            gload16(Bh + bO + kn, REG(nb, 2) + wdst);
            asm volatile("s_waitcnt vmcnt(6)" ::: "memory");
        } else if (t + 1 < nt) {
            asm volatile("s_waitcnt vmcnt(4)" ::: "memory");
        } else {
            asm volatile("s_waitcnt vmcnt(0)" ::: "memory");
        }
        BAR();
        bf16x8 ah[4], bh[2], bl[2], al[4];
        #pragma unroll
        for (int i = 0; i < 4; ++i) ah[i] = *(const bf16x8*)(LAh + aRd[i]);
        #pragma unroll
        for (int j = 0; j < 2; ++j) bh[j] = *(const bf16x8*)(LBh + bRd[j]);
        __builtin_amdgcn_s_setprio(1);
        #pragma unroll
        for (int i = 0; i < 4; ++i)
            #pragma unroll
            for (int j = 0; j < 2; ++j)
                acc[i][j] = __builtin_amdgcn_mfma_f32_16x16x32_bf16(ah[i], bh[j], acc[i][j], 0, 0, 0);
        __builtin_amdgcn_s_setprio(0);
        BAR();

        // ---------- phase 1: read bl; stage Al(t+2); ah*bl ----------
        #pragma unroll
        for (int j = 0; j < 2; ++j) bl[j] = *(const bf16x8*)(LBl + bRd[j]);
        if (t + 2 < nt) gload16(Al + aO + kn, REG(nb, 1) + wdst);
        BAR();
        __builtin_amdgcn_s_setprio(1);
        #pragma unroll
        for (int i = 0; i < 4; ++i)
            #pragma unroll
            for (int j = 0; j < 2; ++j)
                acc[i][j] = __builtin_amdgcn_mfma_f32_16x16x32_bf16(ah[i], bl[j], acc[i][j], 0, 0, 0);
        __builtin_amdgcn_s_setprio(0);
        BAR();

        // ---------- phase 2: read al; stage Bl(t+2); al*bh ----------
        #pragma unroll
        for (int i = 0; i < 4; ++i) al[i] = *(const bf16x8*)(LAl + aRd[i]);
        if (t + 2 < nt) gload16(Bl + bO + kn, REG(nb, 3) + wdst);
        BAR();
        __builtin_amdgcn_s_setprio(1);
        #pragma unroll
        for (int i = 0; i < 4; ++i)
            #pragma unroll
            for (int j = 0; j < 2; ++j)
                acc[i][j] = __builtin_amdgcn_mfma_f32_16x16x32_bf16(al[i], bh[j], acc[i][j], 0, 0, 0);
        __builtin_amdgcn_s_setprio(0);
        BAR();

        cur = (cur + 1 == 3) ? 0 : cur + 1;
    }

    // epilogue: raw partial store (bias/relu deferred to amp_bn)
    #pragma unroll
    for (int i = 0; i < 4; ++i) {
        const int mb = m0 + wm * 64 + i * 16 + lg * 4;
        #pragma unroll
        for (int j = 0; j < 2; ++j) {
            const int n = n0 + wn * 32 + j * 16 + lr;
            #pragma unroll
            for (int q = 0; q < 4; ++q)
                C[(size_t)(mb + q) * NP + n] = acc[i][j][q];
        }
    }
}

// ---------------------------------------------------------------------------
// Split-K reduce + bias + relu + AngularMaxPooling + BatchNorm.
__global__ __launch_bounds__(256) void amp_bn(
    const float* __restrict__ conv,   // 2 partial buffers (MP, NP), CONVSZ apart
    const float* __restrict__ bias,
    const float* __restrict__ g,  const float* __restrict__ be,
    const float* __restrict__ mu, const float* __restrict__ var,
    float* __restrict__ xout)         // (VN, 100)
{
    int v = blockIdx.x * 4 + (threadIdx.x >> 6);
    int lane = threadIdx.x & 63;
    if (v >= VN) return;
    const float* y0 = conv + (size_t)v * NP;
    const float* y1 = y0 + CONVSZ;

    const float bLo = bias[lane];
    const float bHi = (lane < 36) ? bias[64 + lane] : 0.f;

    float t1[8], t2[8], s[8];
    #pragma unroll
    for (int n = 0; n < 8; ++n) {
        float a = fmaxf(y0[n * TN + lane] + y1[n * TN + lane] + bLo, 0.f);
        float b = (lane < 36)
            ? fmaxf(y0[n * TN + 64 + lane] + y1[n * TN + 64 + lane] + bHi, 0.f) : 0.f;
        t1[n] = a; t2[n] = b;
        s[n] = a * a + b * b;
    }
    #pragma unroll
    for (int off = 32; off > 0; off >>= 1)
        #pragma unroll
        for (int n = 0; n < 8; ++n) s[n] += __shfl_xor(s[n], off);

    int best = 0; float bs = s[0];
    #pragma unroll
    for (int n = 1; n < 8; ++n) { if (s[n] > bs) { bs = s[n]; best = n; } }

    float a = t1[0], b = t2[0];
    #pragma unroll
    for (int n = 1; n < 8; ++n) { if (best == n) { a = t1[n]; b = t2[n]; } }

    {
        float inv = 1.0f / sqrtf(var[lane] + 1e-3f);
        xout[v * TN + lane] = g[lane] * (a - mu[lane]) * inv + be[lane];
    }
    if (lane < 36) {
        int t = 64 + lane;
        float inv = 1.0f / sqrtf(var[t] + 1e-3f);
        xout[v * TN + t] = g[t] * (b - mu[t]) * inv + be[t];
    }
}

// ---------------------------------------------------------------------------
// fp32 fallback SGEMM for the dense head (workspace too small case).
template<bool CONV_EPI>
__global__ __launch_bounds__(256, 4) void tile_gemm(
    const float* __restrict__ A, const float* __restrict__ B,
    const float* __restrict__ bias, float* __restrict__ C,
    int M, int N, int K)
{
    __shared__ __align__(16) float As[32][132];
    __shared__ __align__(16) float Bs[32][68];

    const int tid = threadIdx.x;
    const int m0 = blockIdx.x * 128;
    const int n0 = blockIdx.y * 64;
    const int ty = tid >> 4;
    const int tx = tid & 15;
    const int nkt = (K + 31) >> 5;

    float4 aR[4];
    float2 bR[4];

    auto load_tile = [&](int kt) {
        const int k0 = kt << 5;
        #pragma unroll
        for (int j = 0; j < 4; ++j) {
            int q = tid + 256 * j;
            int row = q >> 3, kq = (q & 7) << 2;
            int v = m0 + row, k = k0 + kq;
            if (v < M && k < K)
                aR[j] = *reinterpret_cast<const float4*>(A + (size_t)v * K + k);
            else
                aR[j] = make_float4(0.f, 0.f, 0.f, 0.f);
        }
        #pragma unroll
        for (int j = 0; j < 2; ++j) {
            int q = tid + 256 * j;
            int krow = q >> 4, nq = (q & 15) << 2;
            int k = k0 + krow, n = n0 + nq;
            bR[2 * j]     = (k < K && n + 1 < N)
                ? *reinterpret_cast<const float2*>(B + (size_t)k * N + n)     : make_float2(0.f, 0.f);
            bR[2 * j + 1] = (k < K && n + 3 < N)
                ? *reinterpret_cast<const float2*>(B + (size_t)k * N + n + 2) : make_float2(0.f, 0.f);
        }
    };
    auto stage = [&]() {
        #pragma unroll
        for (int j = 0; j < 4; ++j) {
            int q = tid + 256 * j;
            int row = q >> 3, kq = (q & 7) << 2;
            As[kq + 0][row] = aR[j].x; As[kq + 1][row] = aR[j].y;
            As[kq + 2][row] = aR[j].z; As[kq + 3][row] = aR[j].w;
        }
        #pragma unroll
        for (int j = 0; j < 2; ++j) {
            int q = tid + 256 * j;
            int krow = q >> 4, nq = (q & 15) << 2;
            *reinterpret_cast<float2*>(&Bs[krow][nq])     = bR[2 * j];
            *reinterpret_cast<float2*>(&Bs[krow][nq + 2]) = bR[2 * j + 1];
        }
    };

    float acc[8][4];
    #pragma unroll
    for (int i = 0; i < 8; ++i)
        #pragma unroll
        for (int j = 0; j < 4; ++j) acc[i][j] = 0.f;

    load_tile(0);
    stage();
    __syncthreads();

    for (int kt = 0; kt < nkt; ++kt) {
        if (kt + 1 < nkt) load_tile(kt + 1);
        #pragma unroll 16
        for (int k = 0; k < 32; ++k) {
            float4 a0 = *reinterpret_cast<const float4*>(&As[k][ty * 8]);
            float4 a1 = *reinterpret_cast<const float4*>(&As[k][ty * 8 + 4]);
            float4 b  = *reinterpret_cast<const float4*>(&Bs[k][tx * 4]);
            float av[8] = {a0.x, a0.y, a0.z, a0.w, a1.x, a1.y, a1.z, a1.w};
            float bv[4] = {b.x, b.y, b.z, b.w};
            #pragma unroll
            for (int i = 0; i < 8; ++i)
                #pragma unroll
                for (int j = 0; j < 4; ++j)
                    acc[i][j] = fmaf(av[i], bv[j], acc[i][j]);
        }
        __syncthreads();
        if (kt + 1 < nkt) { stage(); __syncthreads(); }
    }

    #pragma unroll
    for (int i = 0; i < 8; ++i) {
        int vr = m0 + ty * 8 + i;
        if (vr >= M) continue;
        int nb = n0 + tx * 4;
        size_t base = (size_t)vr * N + nb;
        if (nb + 1 < N) {
            float2 o = {acc[i][0] + bias[nb], acc[i][1] + bias[nb + 1]};
            *reinterpret_cast<float2*>(C + base) = o;
        }
        if (nb + 3 < N) {
            float2 o = {acc[i][2] + bias[nb + 2], acc[i][3] + bias[nb + 3]};
            *reinterpret_cast<float2*>(C + base + 2) = o;
        }
    }
}

// ---------------------------------------------------------------------------
// dense-head operand conversion (split bf16, padded to MP x 128)
__global__ __launch_bounds__(256) void dense_a_split(
    const float* __restrict__ xA, short* __restrict__ Ah, short* __restrict__ Al)
{
    int i = blockIdx.x * 256 + threadIdx.x;
    if (i >= MP * 128) return;
    int v = i >> 7, k = i & 127;
    float f = (v < VN && k < TN) ? xA[v * TN + k] : 0.f;
    short h, l; split_bf16(f, &h, &l);
    Ah[i] = h; Al[i] = l;
}
__global__ __launch_bounds__(256) void dense_b_split(
    const float* __restrict__ dw, short* __restrict__ Bh, short* __restrict__ Bl)
{
    int i = blockIdx.x * 256 + threadIdx.x;
    if (i >= MP * 128) return;
    int n = i >> 7, k = i & 127;
    float f = (n < VN && k < TN) ? dw[(size_t)k * VN + n] : 0.f;
    short h, l; split_bf16(f, &h, &l);
    Bh[i] = h; Bl[i] = l;
}

// ---------------------------------------------------------------------------
extern "C" void kernel_launch(void* const* d_in, const int* in_sizes, int n_in,
                              void* d_out, int out_size, void* d_ws, size_t ws_size,
                              hipStream_t stream) {
    const float* signal = (const float*)d_in[0];
    const int*   bcix   = (const int*)  d_in[1];
    const float* bcw    = (const float*)d_in[2];
    const float* nmean  = (const float*)d_in[3];
    const float* nvar   = (const float*)d_in[4];
    const float* w0     = (const float*)d_in[5];
    const float* b0     = (const float*)d_in[6];
    const float* w1     = (const float*)d_in[7];
    const float* b1     = (const float*)d_in[8];
    const float* w2     = (const float*)d_in[9];
    const float* b2     = (const float*)d_in[10];
    const float* bng    = (const float*)d_in[11];
    const float* bnb    = (const float*)d_in[12];
    const float* bnm    = (const float*)d_in[13];
    const float* bnv    = (const float*)d_in[14];
    const float* dw     = (const float*)d_in[15];
    const float* db     = (const float*)d_in[16];
    float* out = (float*)d_out;

    // workspace: small activations
    float* x0 = (float*)d_ws;
    float* xA = x0 + 20736;
    float* xB = xA + 689024;
    short* dAh = (short*)xB;
    short* dAl = dAh + (size_t)MP * 128;
    short* dBh = dAl + (size_t)MP * 128;
    short* dBl = dBh + (size_t)MP * 128;
    const size_t ws_need = (size_t)709760 * 4 + (size_t)4 * MP * 128 * 2;
    const bool dense_mfma = ws_size >= ws_need;

    // big scratch in d_out (dead until dense):
    short* Ph  = (short*)out;
    short* Pl  = Ph  + (size_t)MP * 4000;
    short* Bth = Pl  + (size_t)MP * 4000;
    short* Btl = Bth + (size_t)NP * 4000;
    float* conv = out + (size_t)MP * 4000 + (size_t)NP * 4000;

    dim3 cgrid(MP / 128, NP / 128, 2);     // layer-0 proven kernel
    dim3 c8grid(MP / 128, NP / 128, 2);    // 54 x 7 x 2 = 756 blocks, 512 thr
    dim3 mgrid(MP / 128, MP / 128, 1);
    dim3 dgrid((VN + 127) / 128, (VN + 63) / 64);
    int ampg = (VN + 3) / 4;

    norm_kernel<<<(VN * 3 + 255) / 256, 256, 0, stream>>>(signal, nmean, nvar, x0);

    // layer 0 (CIN=3, K=128 padded, split-K 64+64) — proven kernel
    rotw_split<3, 128><<<NP, 256, 0, stream>>>(w0, Bth, Btl);
    patch_split<3, 128><<<MP, 256, 0, stream>>>(x0, bcix, bcw, Ph, Pl);
    mfma_gemm<true><<<cgrid, 256, 0, stream>>>(Ph, Pl, Bth, Btl, b0, conv, VN, NOUT, NP, 128, 64, CONVSZ);
    amp_bn<<<ampg, 256, 0, stream>>>(conv, b0, bng, bnb, bnm, bnv, xA);

    // layer 1 (K=4000, split-K 2016+1984) — NEW phase-interleaved kernel
    rotw_split<100, 4000><<<NP, 256, 0, stream>>>(w1, Bth, Btl);
    patch_split<100, 4000><<<MP, 256, 0, stream>>>(xA, bcix, bcw, Ph, Pl);
    mfma_conv512<<<c8grid, 512, 0, stream>>>(Ph, Pl, Bth, Btl, conv, 4000, 2016, CONVSZ);
    amp_bn<<<ampg, 256, 0, stream>>>(conv, b1, bng + 100, bnb + 100, bnm + 100, bnv + 100, xB);

    // layer 2 — NEW kernel
    rotw_split<100, 4000><<<NP, 256, 0, stream>>>(w2, Bth, Btl);
    patch_split<100, 4000><<<MP, 256, 0, stream>>>(xB, bcix, bcw, Ph, Pl);
    mfma_conv512<<<c8grid, 512, 0, stream>>>(Ph, Pl, Bth, Btl, conv, 4000, 2016, CONVSZ);
    amp_bn<<<ampg, 256, 0, stream>>>(conv, b2, bng + 200, bnb + 200, bnm + 200, bnv + 200, xA);

    // dense head (K=128 padded, N=V) — proven kernel
    if (dense_mfma) {
        dense_a_split<<<(MP * 128 + 255) / 256, 256, 0, stream>>>(xA, dAh, dAl);
        dense_b_split<<<(MP * 128 + 255) / 256, 256, 0, stream>>>(dw, dBh, dBl);
        mfma_gemm<false><<<mgrid, 256, 0, stream>>>(dAh, dAl, dBh, dBl, db, out, VN, VN, VN, 128, 128, 0);
    } else {
        tile_gemm<false><<<dgrid, 256, 0, stream>>>(xA, dw, db, out, VN, VN, TN);
    }
}

// Round 7
// 740.926 us; speedup vs baseline: 2.4989x; 1.0018x over previous
//
#include <hip/hip_runtime.h>

#define VN 6890
#define TN 100
#define NOUT 800   // 8 rotations * 100 templates
#define MP 6912    // VN padded to 54*128
#define NP 896     // NOUT padded to 7*128
#define CONVSZ (MP * NP)   // one split-K partial buffer (floats)

typedef __attribute__((ext_vector_type(8))) short bf16x8;
typedef __attribute__((ext_vector_type(4))) float f32x4;

#define BAR() do { asm volatile("" ::: "memory"); __builtin_amdgcn_s_barrier(); asm volatile("" ::: "memory"); } while (0)

// ---------------------------------------------------------------------------
// helpers
__device__ __forceinline__ unsigned short f2bf(float f) {
    unsigned u = __float_as_uint(f);
    return (unsigned short)((u + 0x7FFFu + ((u >> 16) & 1u)) >> 16);
}
__device__ __forceinline__ void split_bf16(float f, short* h, short* l) {
    unsigned short hb = f2bf(f);
    float hf = __uint_as_float(((unsigned)hb) << 16);
    *h = (short)hb;
    *l = (short)f2bf(f - hf);
}
__device__ __forceinline__ void gload16(const short* g, void* lds) {
    __builtin_amdgcn_global_load_lds(
        (const __attribute__((address_space(1))) void*)g,
        (__attribute__((address_space(3))) void*)lds, 16, 0, 0);
}

// ---------------------------------------------------------------------------
__global__ __launch_bounds__(256) void norm_kernel(
    const float* __restrict__ sig, const float* __restrict__ mean,
    const float* __restrict__ var, float* __restrict__ x0)
{
    int i = blockIdx.x * blockDim.x + threadIdx.x;
    if (i < VN * 3) {
        int c = i % 3;
        x0[i] = (sig[i] - mean[c]) / sqrtf(var[c]);
    }
}

// ---------------------------------------------------------------------------
// Rotated weights, TRANSPOSED + split:  Bt[n][k] = W[t, r, (a+rot)&7, c]
template<int CIN, int KPAD>
__global__ __launch_bounds__(256) void rotw_split(
    const float* __restrict__ W, short* __restrict__ Bh, short* __restrict__ Bl)
{
    const int n = blockIdx.x;          // 0..NP-1
    const int K = 40 * CIN;
    const int rot = n / TN, t = n - rot * TN;
    for (int k = threadIdx.x; k < KPAD; k += 256) {
        float w = 0.f;
        if (n < NOUT && k < K) {
            int ra = k / CIN, c = k - ra * CIN;
            int r = ra >> 3, a = ra & 7;
            int a2 = (a + rot) & 7;
            w = W[((t * 5 + r) * 8 + a2) * CIN + c];
        }
        short h, l; split_bf16(w, &h, &l);
        Bh[(size_t)n * KPAD + k] = h;
        Bl[(size_t)n * KPAD + k] = l;
    }
}

// ---------------------------------------------------------------------------
// Barycentric patch, split to bf16 hi/lo:  P[v][ra*CIN+c], rows padded to MP.
template<int CIN, int KPAD>
__global__ __launch_bounds__(256) void patch_split(
    const float* __restrict__ x, const int* __restrict__ bidx,
    const float* __restrict__ bw, short* __restrict__ Ph, short* __restrict__ Pl)
{
    __shared__ int   sIdx[120];
    __shared__ float sW[120];
    const int v = blockIdx.x;
    const int tid = threadIdx.x;
    const int K = 40 * CIN;
    if (v >= VN) {
        for (int e = tid; e < KPAD; e += 256) {
            Ph[(size_t)v * KPAD + e] = 0;
            Pl[(size_t)v * KPAD + e] = 0;
        }
        return;
    }
    if (tid < 120) { sIdx[tid] = bidx[v * 120 + tid]; sW[tid] = bw[v * 120 + tid]; }
    __syncthreads();
    for (int e = tid; e < KPAD; e += 256) {
        float s = 0.f;
        if (e < K) {
            int ra = e / CIN, c = e - ra * CIN;
            s = sW[ra * 3 + 0] * x[sIdx[ra * 3 + 0] * CIN + c]
              + sW[ra * 3 + 1] * x[sIdx[ra * 3 + 1] * CIN + c]
              + sW[ra * 3 + 2] * x[sIdx[ra * 3 + 2] * CIN + c];
        }
        short h, l; split_bf16(s, &h, &l);
        Ph[(size_t)v * KPAD + e] = h;
        Pl[(size_t)v * KPAD + e] = l;
    }
}

// ---------------------------------------------------------------------------
// PROVEN 2-barrier split-bf16 MFMA GEMM. Used for layer 0 and the dense head.
template<bool CONV_EPI>
__global__ __launch_bounds__(256, 2) void mfma_gemm(
    const short* __restrict__ Ah, const short* __restrict__ Al,
    const short* __restrict__ Bh, const short* __restrict__ Bl,
    const float* __restrict__ bias, float* __restrict__ C,
    int M, int N, int ldc, int K, int Ksl, int cstride)
{
    __shared__ __align__(16) short AhS[4096];
    __shared__ __align__(16) short AlS[4096];
    __shared__ __align__(16) short BhS[4096];
    __shared__ __align__(16) short BlS[4096];

    const int tid  = threadIdx.x;
    const int wave = tid >> 6;
    const int lane = tid & 63;
    const int lr = lane & 15, lg = lane >> 4;
    const int wm = wave >> 1, wn = wave & 1;
    const int m0 = blockIdx.x * 128;
    const int n0 = blockIdx.y * 128;
    const int kbase = blockIdx.z * Ksl;
    const int kcnt  = min(Ksl, K - kbase);
    if (CONV_EPI) C += (size_t)blockIdx.z * cstride;

    const int off0 = tid * 16, off1 = off0 + 4096;
    const int row0 = off0 >> 6, row1 = off1 >> 6;
    const int g0 = ((off0 >> 4) & 3) ^ ((row0 >> 1) & 3);
    const int g1 = ((off1 >> 4) & 3) ^ ((row1 >> 1) & 3);
    const size_t aO0 = (size_t)(m0 + row0) * K + kbase + g0 * 8;
    const size_t aO1 = (size_t)(m0 + row1) * K + kbase + g1 * 8;
    const size_t bO0 = (size_t)(n0 + row0) * K + kbase + g0 * 8;
    const size_t bO1 = (size_t)(n0 + row1) * K + kbase + g1 * 8;
    const int wofs = wave << 10;

    int aRd[4], bRd[4];
    #pragma unroll
    for (int f = 0; f < 4; ++f) {
        int ar = wm * 64 + f * 16 + lr;
        aRd[f] = ar * 64 + ((lg ^ ((ar >> 1) & 3)) << 4);
        int br = wn * 64 + f * 16 + lr;
        bRd[f] = br * 64 + ((lg ^ ((br >> 1) & 3)) << 4);
    }

    f32x4 acc[4][4];
    #pragma unroll
    for (int i = 0; i < 4; ++i)
        #pragma unroll
        for (int j = 0; j < 4; ++j)
            acc[i][j] = (f32x4){0.f, 0.f, 0.f, 0.f};

    const int nkt = kcnt >> 5;
    for (int kt = 0; kt < nkt; ++kt) {
        const int k0 = kt << 5;
        gload16(Ah + aO0 + k0, (char*)AhS + wofs);
        gload16(Ah + aO1 + k0, (char*)AhS + 4096 + wofs);
        gload16(Al + aO0 + k0, (char*)AlS + wofs);
        gload16(Al + aO1 + k0, (char*)AlS + 4096 + wofs);
        gload16(Bh + bO0 + k0, (char*)BhS + wofs);
        gload16(Bh + bO1 + k0, (char*)BhS + 4096 + wofs);
        gload16(Bl + bO0 + k0, (char*)BlS + wofs);
        gload16(Bl + bO1 + k0, (char*)BlS + 4096 + wofs);
        __syncthreads();

        bf16x8 ah[4], al[4], bh[4], bl[4];
        #pragma unroll
        for (int f = 0; f < 4; ++f) {
            ah[f] = *(const bf16x8*)((const char*)AhS + aRd[f]);
            al[f] = *(const bf16x8*)((const char*)AlS + aRd[f]);
            bh[f] = *(const bf16x8*)((const char*)BhS + bRd[f]);
            bl[f] = *(const bf16x8*)((const char*)BlS + bRd[f]);
        }
        #pragma unroll
        for (int i = 0; i < 4; ++i)
            #pragma unroll
            for (int j = 0; j < 4; ++j)
                acc[i][j] = __builtin_amdgcn_mfma_f32_16x16x32_bf16(ah[i], bh[j], acc[i][j], 0, 0, 0);
        #pragma unroll
        for (int i = 0; i < 4; ++i)
            #pragma unroll
            for (int j = 0; j < 4; ++j)
                acc[i][j] = __builtin_amdgcn_mfma_f32_16x16x32_bf16(ah[i], bl[j], acc[i][j], 0, 0, 0);
        #pragma unroll
        for (int i = 0; i < 4; ++i)
            #pragma unroll
            for (int j = 0; j < 4; ++j)
                acc[i][j] = __builtin_amdgcn_mfma_f32_16x16x32_bf16(al[i], bh[j], acc[i][j], 0, 0, 0);
        __syncthreads();
    }

    #pragma unroll
    for (int i = 0; i < 4; ++i) {
        const int mb = m0 + wm * 64 + i * 16 + lg * 4;
        #pragma unroll
        for (int j = 0; j < 4; ++j) {
            const int n = n0 + wn * 64 + j * 16 + lr;
            if (CONV_EPI) {
                #pragma unroll
                for (int q = 0; q < 4; ++q)
                    C[(size_t)(mb + q) * ldc + n] = acc[i][j][q];
            } else {
                if (n < N) {
                    const float bv = bias[n];
                    #pragma unroll
                    for (int q = 0; q < 4; ++q)
                        if (mb + q < M)
                            C[(size_t)(mb + q) * ldc + n] = acc[i][j][q] + bv;
                }
            }
        }
    }
}

// ---------------------------------------------------------------------------
// Tri-buffered counted-vmcnt split-bf16 MFMA GEMM (layers 1/2).
// 128x128 tile, BK=32, 256 threads (4 waves 2x2, per-wave 64x64 = 16 reads /
// 48 MFMA per tile, ratio 3.0). LDS = 3 bufs x 4 regions x 8KB = 96 KiB,
// 1 block/CU. ONE barrier per K-tile; vmcnt(8) counted wait (never 0 until
// the last tile). Prefetch distance 2: tile x's 8 gloads issue during tile
// x-2. Ledger: at top of tile t outstanding = {t:8, t+1:8}; vmcnt(8)
// retires t's; BAR makes it collective. WAR: issue(t+2) writes buf (t+2)%3
// = (t-1)%3, whose reads completed before tile t's BAR. Requires nt >= 1.
// Grid: x = n (fast) so the 7 same-A-panel blocks are co-resident (L2 reuse).
__global__ __launch_bounds__(256, 1) void conv_tri(
    const short* __restrict__ Ah, const short* __restrict__ Al,
    const short* __restrict__ Bh, const short* __restrict__ Bl,
    float* __restrict__ C, int K, int Ksl, int cstride)
{
    __shared__ __align__(16) short LDS[3 * 4 * 4096];   // 96 KiB

    const int tid  = threadIdx.x;
    const int wave = tid >> 6;
    const int lane = tid & 63;
    const int lr = lane & 15, lg = lane >> 4;
    const int wm = wave >> 1, wn = wave & 1;
    const int n0 = blockIdx.x * 128;      // n is the FAST grid dim (A L2 reuse)
    const int m0 = blockIdx.y * 128;
    const int kbase = blockIdx.z * Ksl;
    const int kcnt  = min(Ksl, K - kbase);
    C += (size_t)blockIdx.z * cstride;

    // staging source offsets (inverse-swizzled), two 4KB sweeps per region
    const int off0 = tid * 16, off1 = off0 + 4096;
    const int row0 = off0 >> 6, row1 = off1 >> 6;
    const int g0 = ((off0 >> 4) & 3) ^ ((row0 >> 1) & 3);
    const int g1 = ((off1 >> 4) & 3) ^ ((row1 >> 1) & 3);
    const size_t aO0 = (size_t)(m0 + row0) * K + kbase + g0 * 8;
    const size_t aO1 = (size_t)(m0 + row1) * K + kbase + g1 * 8;
    const size_t bO0 = (size_t)(n0 + row0) * K + kbase + g0 * 8;
    const size_t bO1 = (size_t)(n0 + row1) * K + kbase + g1 * 8;
    const int wofs = wave << 10;    // gload_lds dest: wave-uniform base + lane*16

    // swizzled ds_read byte offsets within a region
    int aRd[4], bRd[4];
    #pragma unroll
    for (int f = 0; f < 4; ++f) {
        int ar = wm * 64 + f * 16 + lr;
        aRd[f] = ar * 64 + ((lg ^ ((ar >> 1) & 3)) << 4);
        int br = wn * 64 + f * 16 + lr;
        bRd[f] = br * 64 + ((lg ^ ((br >> 1) & 3)) << 4);
    }

    f32x4 acc[4][4];
    #pragma unroll
    for (int i = 0; i < 4; ++i)
        #pragma unroll
        for (int j = 0; j < 4; ++j)
            acc[i][j] = (f32x4){0.f, 0.f, 0.f, 0.f};

    const int nt = kcnt >> 5;

    // issue tile x's 8 gloads into buffer x%3 (regions: Ah,Al,Bh,Bl @ 8KB each)
    auto issue = [&](int x) {
        char* buf = (char*)LDS + (x % 3) * 32768;
        const int k0 = x << 5;
        gload16(Ah + aO0 + k0, buf + wofs);
        gload16(Ah + aO1 + k0, buf + 4096 + wofs);
        gload16(Al + aO0 + k0, buf + 8192 + wofs);
        gload16(Al + aO1 + k0, buf + 8192 + 4096 + wofs);
        gload16(Bh + bO0 + k0, buf + 16384 + wofs);
        gload16(Bh + bO1 + k0, buf + 16384 + 4096 + wofs);
        gload16(Bl + bO0 + k0, buf + 24576 + wofs);
        gload16(Bl + bO1 + k0, buf + 24576 + 4096 + wofs);
    };

    issue(0);
    if (nt > 1) issue(1);

    for (int t = 0; t < nt; ++t) {
        if (t + 1 < nt) { asm volatile("s_waitcnt vmcnt(8)" ::: "memory"); }
        else            { asm volatile("s_waitcnt vmcnt(0)" ::: "memory"); }
        BAR();   // collective: every wave's share of tile t is in LDS

        const char* buf = (const char*)LDS + (t % 3) * 32768;
        bf16x8 ah[4], al[4], bh[4], bl[4];
        #pragma unroll
        for (int f = 0; f < 4; ++f) {
            ah[f] = *(const bf16x8*)(buf + aRd[f]);
            al[f] = *(const bf16x8*)(buf + 8192 + aRd[f]);
            bh[f] = *(const bf16x8*)(buf + 16384 + bRd[f]);
            bl[f] = *(const bf16x8*)(buf + 24576 + bRd[f]);
        }
        if (t + 2 < nt) issue(t + 2);   // writes buf (t-1)%3 — reads done pre-BAR

        #pragma unroll
        for (int i = 0; i < 4; ++i)
            #pragma unroll
            for (int j = 0; j < 4; ++j)
                acc[i][j] = __builtin_amdgcn_mfma_f32_16x16x32_bf16(ah[i], bh[j], acc[i][j], 0, 0, 0);
        #pragma unroll
        for (int i = 0; i < 4; ++i)
            #pragma unroll
            for (int j = 0; j < 4; ++j)
                acc[i][j] = __builtin_amdgcn_mfma_f32_16x16x32_bf16(ah[i], bl[j], acc[i][j], 0, 0, 0);
        #pragma unroll
        for (int i = 0; i < 4; ++i)
            #pragma unroll
            for (int j = 0; j < 4; ++j)
                acc[i][j] = __builtin_amdgcn_mfma_f32_16x16x32_bf16(al[i], bh[j], acc[i][j], 0, 0, 0);
        // no trailing barrier: next tile's vmcnt+BAR is the only sync point
    }

    // epilogue: raw partial store (bias/relu deferred to amp_bn)
    #pragma unroll
    for (int i = 0; i < 4; ++i) {
        const int mb = m0 + wm * 64 + i * 16 + lg * 4;
        #pragma unroll
        for (int j = 0; j < 4; ++j) {
            const int n = n0 + wn * 64 + j * 16 + lr;
            #pragma unroll
            for (int q = 0; q < 4; ++q)
                C[(size_t)(mb + q) * NP + n] = acc[i][j][q];
        }
    }
}

// ---------------------------------------------------------------------------
// Split-K reduce + bias + relu + AngularMaxPooling + BatchNorm.
__global__ __launch_bounds__(256) void amp_bn(
    const float* __restrict__ conv,   // 2 partial buffers (MP, NP), CONVSZ apart
    const float* __restrict__ bias,
    const float* __restrict__ g,  const float* __restrict__ be,
    const float* __restrict__ mu, const float* __restrict__ var,
    float* __restrict__ xout)         // (VN, 100)
{
    int v = blockIdx.x * 4 + (threadIdx.x >> 6);
    int lane = threadIdx.x & 63;
    if (v >= VN) return;
    const float* y0 = conv + (size_t)v * NP;
    const float* y1 = y0 + CONVSZ;

    const float bLo = bias[lane];
    const float bHi = (lane < 36) ? bias[64 + lane] : 0.f;

    float t1[8], t2[8], s[8];
    #pragma unroll
    for (int n = 0; n < 8; ++n) {
        float a = fmaxf(y0[n * TN + lane] + y1[n * TN + lane] + bLo, 0.f);
        float b = (lane < 36)
            ? fmaxf(y0[n * TN + 64 + lane] + y1[n * TN + 64 + lane] + bHi, 0.f) : 0.f;
        t1[n] = a; t2[n] = b;
        s[n] = a * a + b * b;
    }
    #pragma unroll
    for (int off = 32; off > 0; off >>= 1)
        #pragma unroll
        for (int n = 0; n < 8; ++n) s[n] += __shfl_xor(s[n], off);

    int best = 0; float bs = s[0];
    #pragma unroll
    for (int n = 1; n < 8; ++n) { if (s[n] > bs) { bs = s[n]; best = n; } }

    float a = t1[0], b = t2[0];
    #pragma unroll
    for (int n = 1; n < 8; ++n) { if (best == n) { a = t1[n]; b = t2[n]; } }

    {
        float inv = 1.0f / sqrtf(var[lane] + 1e-3f);
        xout[v * TN + lane] = g[lane] * (a - mu[lane]) * inv + be[lane];
    }
    if (lane < 36) {
        int t = 64 + lane;
        float inv = 1.0f / sqrtf(var[t] + 1e-3f);
        xout[v * TN + t] = g[t] * (b - mu[t]) * inv + be[t];
    }
}

// ---------------------------------------------------------------------------
// fp32 fallback SGEMM for the dense head (workspace too small case).
template<bool CONV_EPI>
__global__ __launch_bounds__(256, 4) void tile_gemm(
    const float* __restrict__ A, const float* __restrict__ B,
    const float* __restrict__ bias, float* __restrict__ C,
    int M, int N, int K)
{
    __shared__ __align__(16) float As[32][132];
    __shared__ __align__(16) float Bs[32][68];

    const int tid = threadIdx.x;
    const int m0 = blockIdx.x * 128;
    const int n0 = blockIdx.y * 64;
    const int ty = tid >> 4;
    const int tx = tid & 15;
    const int nkt = (K + 31) >> 5;

    float4 aR[4];
    float2 bR[4];

    auto load_tile = [&](int kt) {
        const int k0 = kt << 5;
        #pragma unroll
        for (int j = 0; j < 4; ++j) {
            int q = tid + 256 * j;
            int row = q >> 3, kq = (q & 7) << 2;
            int v = m0 + row, k = k0 + kq;
            if (v < M && k < K)
                aR[j] = *reinterpret_cast<const float4*>(A + (size_t)v * K + k);
            else
                aR[j] = make_float4(0.f, 0.f, 0.f, 0.f);
        }
        #pragma unroll
        for (int j = 0; j < 2; ++j) {
            int q = tid + 256 * j;
            int krow = q >> 4, nq = (q & 15) << 2;
            int k = k0 + krow, n = n0 + nq;
            bR[2 * j]     = (k < K && n + 1 < N)
                ? *reinterpret_cast<const float2*>(B + (size_t)k * N + n)     : make_float2(0.f, 0.f);
            bR[2 * j + 1] = (k < K && n + 3 < N)
                ? *reinterpret_cast<const float2*>(B + (size_t)k * N + n + 2) : make_float2(0.f, 0.f);
        }
    };
    auto stage = [&]() {
        #pragma unroll
        for (int j = 0; j < 4; ++j) {
            int q = tid + 256 * j;
            int row = q >> 3, kq = (q & 7) << 2;
            As[kq + 0][row] = aR[j].x; As[kq + 1][row] = aR[j].y;
            As[kq + 2][row] = aR[j].z; As[kq + 3][row] = aR[j].w;
        }
        #pragma unroll
        for (int j = 0; j < 2; ++j) {
            int q = tid + 256 * j;
            int krow = q >> 4, nq = (q & 15) << 2;
            *reinterpret_cast<float2*>(&Bs[krow][nq])     = bR[2 * j];
            *reinterpret_cast<float2*>(&Bs[krow][nq + 2]) = bR[2 * j + 1];
        }
    };

    float acc[8][4];
    #pragma unroll
    for (int i = 0; i < 8; ++i)
        #pragma unroll
        for (int j = 0; j < 4; ++j) acc[i][j] = 0.f;

    load_tile(0);
    stage();
    __syncthreads();

    for (int kt = 0; kt < nkt; ++kt) {
        if (kt + 1 < nkt) load_tile(kt + 1);
        #pragma unroll 16
        for (int k = 0; k < 32; ++k) {
            float4 a0 = *reinterpret_cast<const float4*>(&As[k][ty * 8]);
            float4 a1 = *reinterpret_cast<const float4*>(&As[k][ty * 8 + 4]);
            float4 b  = *reinterpret_cast<const float4*>(&Bs[k][tx * 4]);
            float av[8] = {a0.x, a0.y, a0.z, a0.w, a1.x, a1.y, a1.z, a1.w};
            float bv[4] = {b.x, b.y, b.z, b.w};
            #pragma unroll
            for (int i = 0; i < 8; ++i)
                #pragma unroll
                for (int j = 0; j < 4; ++j)
                    acc[i][j] = fmaf(av[i], bv[j], acc[i][j]);
        }
        __syncthreads();
        if (kt + 1 < nkt) { stage(); __syncthreads(); }
    }

    #pragma unroll
    for (int i = 0; i < 8; ++i) {
        int vr = m0 + ty * 8 + i;
        if (vr >= M) continue;
        int nb = n0 + tx * 4;
        size_t base = (size_t)vr * N + nb;
        if (nb + 1 < N) {
            float2 o = {acc[i][0] + bias[nb], acc[i][1] + bias[nb + 1]};
            *reinterpret_cast<float2*>(C + base) = o;
        }
        if (nb + 3 < N) {
            float2 o = {acc[i][2] + bias[nb + 2], acc[i][3] + bias[nb + 3]};
            *reinterpret_cast<float2*>(C + base + 2) = o;
        }
    }
}

// ---------------------------------------------------------------------------
// dense-head operand conversion (split bf16, padded to MP x 128)
__global__ __launch_bounds__(256) void dense_a_split(
    const float* __restrict__ xA, short* __restrict__ Ah, short* __restrict__ Al)
{
    int i = blockIdx.x * 256 + threadIdx.x;
    if (i >= MP * 128) return;
    int v = i >> 7, k = i & 127;
    float f = (v < VN && k < TN) ? xA[v * TN + k] : 0.f;
    short h, l; split_bf16(f, &h, &l);
    Ah[i] = h; Al[i] = l;
}
__global__ __launch_bounds__(256) void dense_b_split(
    const float* __restrict__ dw, short* __restrict__ Bh, short* __restrict__ Bl)
{
    int i = blockIdx.x * 256 + threadIdx.x;
    if (i >= MP * 128) return;
    int n = i >> 7, k = i & 127;
    float f = (n < VN && k < TN) ? dw[(size_t)k * VN + n] : 0.f;
    short h, l; split_bf16(f, &h, &l);
    Bh[i] = h; Bl[i] = l;
}

// ---------------------------------------------------------------------------
extern "C" void kernel_launch(void* const* d_in, const int* in_sizes, int n_in,
                              void* d_out, int out_size, void* d_ws, size_t ws_size,
                              hipStream_t stream) {
    const float* signal = (const float*)d_in[0];
    const int*   bcix   = (const int*)  d_in[1];
    const float* bcw    = (const float*)d_in[2];
    const float* nmean  = (const float*)d_in[3];
    const float* nvar   = (const float*)d_in[4];
    const float* w0     = (const float*)d_in[5];
    const float* b0     = (const float*)d_in[6];
    const float* w1     = (const float*)d_in[7];
    const float* b1     = (const float*)d_in[8];
    const float* w2     = (const float*)d_in[9];
    const float* b2     = (const float*)d_in[10];
    const float* bng    = (const float*)d_in[11];
    const float* bnb    = (const float*)d_in[12];
    const float* bnm    = (const float*)d_in[13];
    const float* bnv    = (const float*)d_in[14];
    const float* dw     = (const float*)d_in[15];
    const float* db     = (const float*)d_in[16];
    float* out = (float*)d_out;

    // workspace: small activations
    float* x0 = (float*)d_ws;
    float* xA = x0 + 20736;
    float* xB = xA + 689024;
    short* dAh = (short*)xB;
    short* dAl = dAh + (size_t)MP * 128;
    short* dBh = dAl + (size_t)MP * 128;
    short* dBl = dBh + (size_t)MP * 128;
    const size_t ws_need = (size_t)709760 * 4 + (size_t)4 * MP * 128 * 2;
    const bool dense_mfma = ws_size >= ws_need;

    // big scratch in d_out (dead until dense):
    short* Ph  = (short*)out;
    short* Pl  = Ph  + (size_t)MP * 4000;
    short* Bth = Pl  + (size_t)MP * 4000;
    short* Btl = Bth + (size_t)NP * 4000;
    float* conv = out + (size_t)MP * 4000 + (size_t)NP * 4000;

    dim3 cgrid(MP / 128, NP / 128, 2);     // layer-0 proven kernel (m-fast)
    dim3 tgrid(NP / 128, MP / 128, 2);     // conv_tri: n-FAST for A L2 reuse
    dim3 mgrid(MP / 128, MP / 128, 1);
    dim3 dgrid((VN + 127) / 128, (VN + 63) / 64);
    int ampg = (VN + 3) / 4;

    norm_kernel<<<(VN * 3 + 255) / 256, 256, 0, stream>>>(signal, nmean, nvar, x0);

    // layer 0 (CIN=3, K=128 padded, split-K 64+64) — proven kernel
    rotw_split<3, 128><<<NP, 256, 0, stream>>>(w0, Bth, Btl);
    patch_split<3, 128><<<MP, 256, 0, stream>>>(x0, bcix, bcw, Ph, Pl);
    mfma_gemm<true><<<cgrid, 256, 0, stream>>>(Ph, Pl, Bth, Btl, b0, conv, VN, NOUT, NP, 128, 64, CONVSZ);
    amp_bn<<<ampg, 256, 0, stream>>>(conv, b0, bng, bnb, bnm, bnv, xA);

    // layer 1 (K=4000, split-K 2016+1984) — tri-buffer counted-vmcnt kernel
    rotw_split<100, 4000><<<NP, 256, 0, stream>>>(w1, Bth, Btl);
    patch_split<100, 4000><<<MP, 256, 0, stream>>>(xA, bcix, bcw, Ph, Pl);
    conv_tri<<<tgrid, 256, 0, stream>>>(Ph, Pl, Bth, Btl, conv, 4000, 2016, CONVSZ);
    amp_bn<<<ampg, 256, 0, stream>>>(conv, b1, bng + 100, bnb + 100, bnm + 100, bnv + 100, xB);

    // layer 2 — tri-buffer kernel
    rotw_split<100, 4000><<<NP, 256, 0, stream>>>(w2, Bth, Btl);
    patch_split<100, 4000><<<MP, 256, 0, stream>>>(xB, bcix, bcw, Ph, Pl);
    conv_tri<<<tgrid, 256, 0, stream>>>(Ph, Pl, Bth, Btl, conv, 4000, 2016, CONVSZ);
    amp_bn<<<ampg, 256, 0, stream>>>(conv, b2, bng + 200, bnb + 200, bnm + 200, bnv + 200, xA);

    // dense head (K=128 padded, N=V) — proven kernel
    if (dense_mfma) {
        dense_a_split<<<(MP * 128 + 255) / 256, 256, 0, stream>>>(xA, dAh, dAl);
        dense_b_split<<<(MP * 128 + 255) / 256, 256, 0, stream>>>(dw, dBh, dBl);
        mfma_gemm<false><<<mgrid, 256, 0, stream>>>(dAh, dAl, dBh, dBl, db, out, VN, VN, VN, 128, 128, 0);
    } else {
        tile_gemm<false><<<dgrid, 256, 0, stream>>>(xA, dw, db, out, VN, VN, TN);
    }
}